// Round 11
// baseline (268.188 us; speedup 1.0000x reference)
//
#include <hip/hip_runtime.h>
#include <math.h>

#define TPB 1024      // finalize threads
#define TPBS 256      // streaming kernel threads
#define NS 8          // slices per row
#define NBINS 512     // fallback hist bins
#define CAP 2048
#define NSEL 64
#define MBINS 1024    // deep-row mass hist bins
#define MWIN 16.0f
#define WIN 2.0f      // candidate collect window below max
#define SLCAP 1024    // per-block LDS candidate staging capacity
#define BANDCAP 64    // deferred min-p band elements per row

typedef unsigned long long u64t;

// ---------- key encodings ----------
__device__ __forceinline__ unsigned int ordAsc(float v) {
  unsigned int b = __float_as_uint(v);
  return (b & 0x80000000u) ? ~b : (b | 0x80000000u);
}
__device__ __forceinline__ float ordInv(unsigned int o) {
  return __uint_as_float((o & 0x80000000u) ? (o & 0x7fffffffu) : ~o);
}
__device__ __forceinline__ unsigned int fkeyDesc(float v) { return ~ordAsc(v); }
__device__ __forceinline__ float fkeyInv(unsigned int kd) { return ordInv(~kd); }
// max-key: larger value wins; tie -> smaller index wins
__device__ __forceinline__ u64t mkMaxKey(float v, int idx) {
  return ((u64t)ordAsc(v) << 32) | (unsigned int)(~(unsigned int)idx);
}

// ---------- block reductions ----------
__device__ __forceinline__ float blockSumF(float v, float* sred) {
  #pragma unroll
  for (int o = 32; o > 0; o >>= 1) v += __shfl_down(v, o, 64);
  int wid = threadIdx.x >> 6, lane = threadIdx.x & 63, nw = blockDim.x >> 6;
  __syncthreads();
  if (lane == 0) sred[wid] = v;
  __syncthreads();
  if (threadIdx.x == 0) { float r = sred[0]; for (int w = 1; w < nw; ++w) r += sred[w]; sred[0] = r; }
  __syncthreads();
  float r = sred[0];
  __syncthreads();
  return r;
}
__device__ __forceinline__ int blockSumI(int v, int* sred) {
  #pragma unroll
  for (int o = 32; o > 0; o >>= 1) v += __shfl_down(v, o, 64);
  int wid = threadIdx.x >> 6, lane = threadIdx.x & 63, nw = blockDim.x >> 6;
  __syncthreads();
  if (lane == 0) sred[wid] = v;
  __syncthreads();
  if (threadIdx.x == 0) { int r = sred[0]; for (int w = 1; w < nw; ++w) r += sred[w]; sred[0] = r; }
  __syncthreads();
  int r = sred[0];
  __syncthreads();
  return r;
}
__device__ __forceinline__ int blockMaxI(int v, int* sred) {
  #pragma unroll
  for (int o = 32; o > 0; o >>= 1) { int v2 = __shfl_down(v, o, 64); if (v2 > v) v = v2; }
  int wid = threadIdx.x >> 6, lane = threadIdx.x & 63, nw = blockDim.x >> 6;
  __syncthreads();
  if (lane == 0) sred[wid] = v;
  __syncthreads();
  if (threadIdx.x == 0) { int r = sred[0]; for (int w = 1; w < nw; ++w) if (sred[w] > r) r = sred[w]; sred[0] = r; }
  __syncthreads();
  int r = sred[0];
  __syncthreads();
  return r;
}
__device__ __forceinline__ u64t blockMaxU64(u64t v, u64t* sred) {
  #pragma unroll
  for (int o = 32; o > 0; o >>= 1) { u64t v2 = __shfl_down(v, o, 64); if (v2 > v) v = v2; }
  int wid = threadIdx.x >> 6, lane = threadIdx.x & 63, nw = blockDim.x >> 6;
  __syncthreads();
  if (lane == 0) sred[wid] = v;
  __syncthreads();
  if (threadIdx.x == 0) { u64t r = sred[0]; for (int w = 1; w < nw; ++w) if (sred[w] > r) r = sred[w]; sred[0] = r; }
  __syncthreads();
  u64t r = sred[0];
  __syncthreads();
  return r;
}
__device__ __forceinline__ void blockArgMaxF(float& v, int& idx, float* sredf, int* sredi) {
  #pragma unroll
  for (int o = 32; o > 0; o >>= 1) {
    float v2 = __shfl_down(v, o, 64);
    int  i2 = __shfl_down(idx, o, 64);
    if (v2 > v || (v2 == v && i2 < idx)) { v = v2; idx = i2; }
  }
  int wid = threadIdx.x >> 6, lane = threadIdx.x & 63, nw = blockDim.x >> 6;
  __syncthreads();
  if (lane == 0) { sredf[wid] = v; sredi[wid] = idx; }
  __syncthreads();
  if (threadIdx.x == 0) {
    float bv = sredf[0]; int bi = sredi[0];
    for (int w = 1; w < nw; ++w) {
      float v2 = sredf[w]; int i2 = sredi[w];
      if (v2 > bv || (v2 == bv && i2 < bi)) { bv = v2; bi = i2; }
    }
    sredf[0] = bv; sredi[0] = bi;
  }
  __syncthreads();
  v = sredf[0]; idx = sredi[0];
  __syncthreads();
}

__device__ void bitonicSortN(u64t* keys, int n) {
  for (unsigned int k = 2; k <= (unsigned int)n; k <<= 1) {
    for (unsigned int j = k >> 1; j > 0; j >>= 1) {
      __syncthreads();
      for (unsigned int i = threadIdx.x; i < (unsigned int)n; i += blockDim.x) {
        unsigned int ixj = i ^ j;
        if (ixj > i) {
          u64t a = keys[i], b = keys[ixj];
          bool up = ((i & k) == 0);
          if ((a > b) == up) { keys[i] = b; keys[ixj] = a; }
        }
      }
    }
  }
  __syncthreads();
}

// hybrid register bitonic: n==1024, block must be 1024 threads.
__device__ u64t bitonicReg1024(u64t key, u64t* lds) {
  const int tid = threadIdx.x;
  for (unsigned int k = 2; k <= 1024; k <<= 1) {
    for (unsigned int j = k >> 1; j > 0; j >>= 1) {
      u64t partner;
      if (j >= 64) {
        __syncthreads();
        lds[tid] = key;
        __syncthreads();
        partner = lds[tid ^ j];
      } else {
        partner = __shfl_xor((unsigned long long)key, (int)j, 64);
      }
      bool up = ((tid & k) == 0);
      bool lower = ((tid & j) == 0);
      bool keepSmaller = (up == lower);
      bool pSmaller = (partner < key);
      if (keepSmaller == pSmaller) key = partner;
    }
  }
  __syncthreads();
  lds[tid] = key;
  __syncthreads();
  return key;
}

// combine rescaled S0 from per-slice (local-max) sums
__device__ __forceinline__ float combineS0(const u64t* smax, const float* s0s, float m0) {
  float S0 = 0.f;
  for (int w = 0; w < NS; ++w) {
    float ms = ordInv((unsigned int)(smax[w] >> 32));
    S0 += s0s[w] * expf(ms - m0);
  }
  return S0;
}

// =================== K1: single-pass slice max+argmax + online S0 sum ===================
__global__ __launch_bounds__(TPBS) void k1_max(const float* __restrict__ logits,
                                               u64t* __restrict__ maxes,
                                               float* __restrict__ s0_ws,
                                               int* __restrict__ ccnt,
                                               int* __restrict__ bandcnt, int V) {
  const int row = blockIdx.y, s = blockIdx.x, tid = threadIdx.x;
  if (s == 0 && tid == 0) { ccnt[row] = 0; bandcnt[row] = 0; }
  const float* x = logits + (size_t)row * V;
  const int V4 = V >> 2;
  const float4* x4 = (const float4*)x;
  const int a4 = (int)(((long long)V4 * s) / NS), b4 = (int)(((long long)V4 * (s + 1)) / NS);
  u64t best = 0ull;
  float mt = -INFINITY, s0 = 0.f;
  auto body = [&](float vv, int gi) {
    u64t k = mkMaxKey(vv, gi);
    if (k > best) best = k;
    if (vv > mt) { s0 = s0 * expf(mt - vv); mt = vv; }   // online rescale
    s0 += expf(vv - mt);
  };
  for (int i4 = a4 + tid; i4 < b4; i4 += TPBS) {
    float4 v = x4[i4]; int b = i4 << 2;
    body(v.x, b); body(v.y, b + 1); body(v.z, b + 2); body(v.w, b + 3);
  }
  if (s == NS - 1) for (int i = (V4 << 2) + tid; i < V; i += TPBS) body(x[i], i);
  __shared__ u64t sredU[16];
  __shared__ float sredF[16];
  best = blockMaxU64(best, sredU);
  if (tid == 0) maxes[row * NS + s] = best;
  const float msv = ordInv((unsigned int)(best >> 32));
  float s0r = s0 * expf(mt - msv);
  float r0 = blockSumF(s0r, sredF);
  if (tid == 0) s0_ws[row * NS + s] = r0;
}

// =================== K2: single streaming pass (S, Sp, ck, candidates, band, mass) ===================
__global__ __launch_bounds__(TPBS) void k2_all(const float* __restrict__ logits,
    const float* __restrict__ temp_arr, const float* __restrict__ minp_arr,
    const int* __restrict__ topk_arr, const u64t* __restrict__ maxes,
    float* __restrict__ sl_ws, float* __restrict__ sp_ws, int* __restrict__ ck_ws,
    int* __restrict__ ccnt, u64t* __restrict__ cand,
    int* __restrict__ bandcnt, u64t* __restrict__ band,
    u64t* __restrict__ mass, int V) {
  const int row = blockIdx.y, s = blockIdx.x, tid = threadIdx.x;
  __shared__ u64t smax[NS];
  __shared__ float sredF[16];
  __shared__ int sredI[16];
  __shared__ u64t lcand[SLCAP];
  __shared__ u64t lmass[MBINS];
  __shared__ int lcnt, lbase;
  const float temp = temp_arr[row];
  const bool greedy = (temp < 1e-5f);
  const int topk = topk_arr[row];
  const bool deep = (!greedy && topk <= 0);
  if (tid < NS) smax[tid] = maxes[row * NS + tid];
  if (tid == 0) lcnt = 0;
  if (deep) for (int b = tid; b < MBINS; b += TPBS) lmass[b] = 0ull;
  __syncthreads();
  u64t mk = smax[0];
  for (int w = 1; w < NS; ++w) { u64t t = smax[w]; if (t > mk) mk = t; }
  const float m0 = ordInv((unsigned int)(mk >> 32));
  const float wlo = m0 - WIN;
  const float* x = logits + (size_t)row * V;
  const int V4 = V >> 2;
  const float4* x4 = (const float4*)x;
  const int a4 = (int)(((long long)V4 * s) / NS), b4 = (int)(((long long)V4 * (s + 1)) / NS);

  if (greedy) {
    auto bodyG = [&](float vv, int gi) {
      if (vv >= wlo) {
        int pos = atomicAdd(&lcnt, 1);
        if (pos < SLCAP) lcand[pos] = ((u64t)fkeyDesc(vv) << 32) | (unsigned int)gi;
      }
    };
    for (int i4 = a4 + tid; i4 < b4; i4 += TPBS) {
      float4 v = x4[i4]; int b = i4 << 2;
      bodyG(v.x, b); bodyG(v.y, b + 1); bodyG(v.z, b + 2); bodyG(v.w, b + 3);
    }
    if (s == NS - 1) for (int i = (V4 << 2) + tid; i < V; i += TPBS) bodyG(x[i], i);
    __syncthreads();
    if (tid == 0) {
      sl_ws[row * NS + s] = 0.f; sp_ws[row * NS + s] = 0.f; ck_ws[row * NS + s] = 0;
      int c = lcnt;
      int add = (c > SLCAP) ? (c + CAP + 1) : c;
      lbase = atomicAdd(&ccnt[row], add);
    }
    __syncthreads();
    int c = lcnt < SLCAP ? lcnt : SLCAP;
    int base = lbase;
    for (int j = tid; j < c; j += TPBS) {
      int pos = base + j;
      if (pos < CAP) cand[(size_t)row * CAP + pos] = lcand[j];
    }
    return;
  }

  const float st = temp;
  const float ml = m0 / st;
  const float minp = minp_arr[row];
  const float bHi = minp * (1.0f + 4e-6f);
  const float bLo = minp * (1.0f - 4e-6f);
  const float scaleM = (float)MBINS / MWIN;
  float sl = 0.f, sp = 0.f; int ckp = 0;
  auto body = [&](float vv, int gi) {
    float l = vv / st;
    float e = expf(l - ml);
    sl += e;
    if (minp <= 0.f || e > bHi) {
      sp += e; ckp++;
      if (deep) {
        float fm = (m0 - vv) * scaleM;
        if (fm < (float)MBINS)
          atomicAdd(&lmass[(int)fm], (u64t)((double)e * 4294967296.0));
      }
    } else if (e >= bLo) {
      int pos = atomicAdd(&bandcnt[row], 1);
      if (pos < BANDCAP)
        band[(size_t)row * BANDCAP + pos] = ((u64t)(unsigned int)gi << 32) | __float_as_uint(vv);
    }
    if (vv >= wlo) {
      int pos = atomicAdd(&lcnt, 1);
      if (pos < SLCAP) lcand[pos] = ((u64t)fkeyDesc(vv) << 32) | (unsigned int)gi;
    }
  };
  for (int i4 = a4 + tid; i4 < b4; i4 += TPBS) {
    float4 v = x4[i4]; int b = i4 << 2;
    body(v.x, b); body(v.y, b + 1); body(v.z, b + 2); body(v.w, b + 3);
  }
  if (s == NS - 1) for (int i = (V4 << 2) + tid; i < V; i += TPBS) body(x[i], i);
  float rl = blockSumF(sl, sredF);
  float rp = blockSumF(sp, sredF);
  int rc = blockSumI(ckp, sredI);
  if (tid == 0) {
    sl_ws[row * NS + s] = rl; sp_ws[row * NS + s] = rp; ck_ws[row * NS + s] = rc;
    int c = lcnt;
    int add = (c > SLCAP) ? (c + CAP + 1) : c;
    lbase = atomicAdd(&ccnt[row], add);
  }
  __syncthreads();
  int c = lcnt < SLCAP ? lcnt : SLCAP;
  int base = lbase;
  for (int j = tid; j < c; j += TPBS) {
    int pos = base + j;
    if (pos < CAP) cand[(size_t)row * CAP + pos] = lcand[j];
  }
  if (deep) {
    u64t* mrow = mass + ((size_t)row * NS + s) * MBINS;
    for (int b = tid; b < MBINS; b += TPBS) mrow[b] = lmass[b];
  }
}

// =================== K5: per-row finalize (non-deep complete; deep -> bp/seed) ===================
__global__ __launch_bounds__(TPB) void k5_final(const float* __restrict__ logits,
    const float* __restrict__ temp_arr, const float* __restrict__ minp_arr,
    const float* __restrict__ topp_arr, const int* __restrict__ topk_arr,
    const float* __restrict__ u_arr, const u64t* __restrict__ maxes,
    const float* __restrict__ s0_ws, const float* __restrict__ sl_ws,
    const float* __restrict__ sp_ws, const int* __restrict__ ck_ws,
    const int* __restrict__ ccnt, const u64t* __restrict__ cand,
    const u64t* __restrict__ mass, const u64t* __restrict__ band,
    const int* __restrict__ bandcnt, float* __restrict__ w_thr,
    int* __restrict__ w_bpM, double* __restrict__ w_seed, float* __restrict__ w_spD,
    float* __restrict__ out, int T, int V, int NL) {
  __shared__ u64t keyA[CAP];
  __shared__ int fh[NBINS];
  __shared__ float sredF[16];
  __shared__ int sredI[16];
  __shared__ u64t smax[NS];
  __shared__ float sp0[NS], spl[NS], spsp[NS];
  __shared__ int spck[NS];
  __shared__ float sh_thresh, sh_toklp, sh_spAdd;
  __shared__ double sh_seed;
  __shared__ int sh_cnt, sh_bp, sh_bCnt, sh_ckAdd;
  __shared__ u64t sh_bKeys[BANDCAP];
  __shared__ u64t sh_bMass[BANDCAP];
  __shared__ int  sh_bBin[BANDCAP];
  __shared__ u64t sel[NSEL];
  __shared__ u64t kb64[NSEL];
  __shared__ u64t kbs[NSEL];

  const int row = blockIdx.x;
  const int tid = threadIdx.x;
  const float* x  = logits + (size_t)row * V;
  const float* uu = u_arr  + (size_t)row * V;
  const float temp = temp_arr[row];
  const float minp = minp_arr[row];
  const float topp = topp_arr[row];
  const int   topk = topk_arr[row];
  const bool greedy = (temp < 1e-5f);
  const float st = greedy ? 1.0f : temp;
  const int V4 = V >> 2;
  const float4* x4 = (const float4*)x;

  if (tid < NS) {
    smax[tid] = maxes[row * NS + tid];
    sp0[tid] = s0_ws[row * NS + tid];
    spl[tid] = sl_ws[row * NS + tid];
    spsp[tid] = sp_ws[row * NS + tid];
    spck[tid] = ck_ws[row * NS + tid];
  }
  __syncthreads();
  u64t mk = smax[0];
  for (int w = 1; w < NS; ++w) { u64t t = smax[w]; if (t > mk) mk = t; }
  const float m0 = ordInv((unsigned int)(mk >> 32));
  const int gidx = (int)(~(unsigned int)mk);
  float S = spl[0], Sp = spsp[0];
  int ck = spck[0];
  for (int w = 1; w < NS; ++w) { S += spl[w]; Sp += spsp[w]; ck += spck[w]; }
  const float S0 = combineS0(smax, sp0, m0);
  const float ml = m0 / st;
  const float logS0 = logf(S0);
  const float rhs = minp * (1.0f / S);
  const float rhsS = rhs * S;
  const float rhsHi = rhsS * (1.0f + 1e-6f);
  const float rhsLo = rhsS * (1.0f - 1e-6f);
  auto keepTest = [&](float e) -> bool {
    if (e > rhsHi) return true;
    if (e < rhsLo) return false;
    return (e / S) >= rhs;
  };
  const bool deep = (!greedy && topk <= 0);
  const float scaleM = (float)MBINS / MWIN;

  // ----- resolve deferred min-p band elements (rare) -----
  const int bandTotal = greedy ? 0 : bandcnt[row];
  const bool bandOv = bandTotal > BANDCAP;
  if (tid == 0) { sh_bCnt = 0; sh_spAdd = 0.f; sh_ckAdd = 0; }
  __syncthreads();
  if (!greedy && !bandOv && bandTotal > 0 && minp > 0.f) {
    if (tid == 0) {
      for (int i = 0; i < bandTotal; ++i) sh_bKeys[i] = band[(size_t)row * BANDCAP + i];
      for (int i = 1; i < bandTotal; ++i) {
        u64t k = sh_bKeys[i]; int j = i - 1;
        while (j >= 0 && sh_bKeys[j] > k) { sh_bKeys[j + 1] = sh_bKeys[j]; j--; }
        sh_bKeys[j + 1] = k;
      }
      float spAdd = 0.f; int ckAdd = 0, bc = 0;
      for (int i = 0; i < bandTotal; ++i) {
        float vv = __uint_as_float((unsigned int)(sh_bKeys[i] & 0xffffffffu));
        float l = vv / st; float e = expf(l - ml);
        if ((e / S) >= rhs) {
          spAdd += e; ckAdd++;
          if (deep) {
            float fm = (m0 - vv) * scaleM;
            if (fm < (float)MBINS) { sh_bBin[bc] = (int)fm; sh_bMass[bc] = (u64t)((double)e * 4294967296.0); bc++; }
          }
        }
      }
      sh_spAdd = spAdd; sh_ckAdd = ckAdd; sh_bCnt = bc;
    }
    __syncthreads();
    Sp += sh_spAdd; ck += sh_ckAdd;
  } else if (!greedy && bandOv) {
    float sp2 = 0.f; int ck2 = 0;
    auto bodyR = [&](float vv) {
      float l = vv / st; float e = expf(l - ml);
      if (keepTest(e)) { sp2 += e; ck2++; }
    };
    for (int i4 = tid; i4 < V4; i4 += TPB) { float4 v = x4[i4]; bodyR(v.x); bodyR(v.y); bodyR(v.z); bodyR(v.w); }
    for (int i = (V4 << 2) + tid; i < V; i += TPB) bodyR(x[i]);
    Sp = blockSumF(sp2, sredF);
    ck = blockSumI(ck2, sredI);
  }

  // ----- candidates -----
  int cc = ccnt[row];
  int Cact = cc < CAP ? cc : CAP;
  int need = NSEL;
  if (topk > need) need = topk;
  if (need > CAP / 2) need = CAP / 2;
  if (need > V) need = V;
  bool fb = (cc > CAP) || (Cact < need);
  if (!fb) {
    for (int j = tid; j < Cact; j += TPB) keyA[j] = cand[(size_t)row * CAP + j];
  } else {
    const float bS = (float)NBINS / MWIN;
    for (int b = tid; b < NBINS; b += TPB) fh[b] = 0;
    if (tid == 0) sh_cnt = 0;
    __syncthreads();
    auto hb = [&](float vv) {
      float fbv = (m0 - vv) * bS;
      if (fbv < (float)NBINS) atomicAdd(&fh[(int)fbv], 1);
    };
    for (int i4 = tid; i4 < V4; i4 += TPB) { float4 v = x4[i4]; hb(v.x); hb(v.y); hb(v.z); hb(v.w); }
    for (int i = (V4 << 2) + tid; i < V; i += TPB) hb(x[i]);
    __syncthreads();
    if (tid == 0) {
      int cum = 0, B = -1;
      for (int b = 0; b < NBINS; ++b) { cum += fh[b]; if (cum >= need) { B = b; break; } }
      if (B < 0) B = NBINS - 1;
      sh_bp = B;
    }
    __syncthreads();
    const int B = sh_bp;
    auto cb = [&](float vv, int gi) {
      float fbv = (m0 - vv) * bS;
      if (fbv < (float)NBINS && (int)fbv <= B) {
        int pos = atomicAdd(&sh_cnt, 1);
        if (pos < CAP) keyA[pos] = ((u64t)fkeyDesc(vv) << 32) | (unsigned int)gi;
      }
    };
    for (int i4 = tid; i4 < V4; i4 += TPB) { float4 v = x4[i4]; int b = i4 << 2; cb(v.x, b); cb(v.y, b + 1); cb(v.z, b + 2); cb(v.w, b + 3); }
    for (int i = (V4 << 2) + tid; i < V; i += TPB) cb(x[i], i);
    __syncthreads();
    Cact = sh_cnt < CAP ? sh_cnt : CAP;
  }
  __syncthreads();

  // ----- top-64 selection: rank-select (need<=NSEL) or full bitonic fallback -----
  bool sortedFull = (need > NSEL);
  if (!sortedFull) {
    for (int j = tid; j < Cact; j += TPB) {
      u64t me = keyA[j];
      int r = 0;
      for (int i = 0; i < Cact; ++i) r += (keyA[i] < me) ? 1 : 0;
      if (r < NSEL) sel[r] = me;
    }
    __syncthreads();
  } else {
    int n = 128; while (n < Cact) n <<= 1;
    for (int i = Cact + tid; i < n; i += TPB) keyA[i] = ~0ull;
    __syncthreads();
    bitonicSortN(keyA, n);
    int M0 = Cact < NSEL ? Cact : NSEL;
    for (int j = tid; j < M0; j += TPB) sel[j] = keyA[j];
    __syncthreads();
  }

  // ----- top-NL by lp via rank-sort of top-64 -----
  {
    int M = Cact < NSEL ? Cact : NSEL;
    if (tid < M) {
      u64t ka = sel[tid];
      float xv = fkeyInv((unsigned int)(ka >> 32));
      float lp = (xv - m0) - logS0;
      kb64[tid] = ((u64t)fkeyDesc(lp) << 32) | (ka & 0xffffffffu);
    }
    __syncthreads();
    if (tid < M) {
      u64t me = kb64[tid];
      int r = 0;
      for (int i = 0; i < M; ++i) r += (kb64[i] < me) ? 1 : 0;
      kbs[r] = me;
    }
    __syncthreads();
    float* o_idx  = out + T;
    float* o_lps  = out + T + (size_t)T * (NL + 1);
    for (int j = tid; j < NL; j += TPB) {
      if (j < M) {
        u64t kb = kbs[j];
        o_idx[(size_t)row * (NL + 1) + 1 + j] = (float)(unsigned int)(kb & 0xffffffffu);
        o_lps[(size_t)row * (NL + 1) + 1 + j] = fkeyInv((unsigned int)(kb >> 32));
      }
    }
  }

  // ----- sampling -----
  int sampled = -1;
  if (greedy) {
    sampled = gidx;
  } else if (topk > 0) {
    if (tid == 0) {
      int k = topk; if (k > V) k = V; if (k > CAP) k = CAP;
      int jp = 0; float cum = 0.f;
      for (int j = 0; j < k; ++j) {
        float pj = 0.f;
        if (j < ck && j < Cact) {
          u64t kj = sortedFull ? keyA[j] : sel[j];
          float xv = fkeyInv((unsigned int)(kj >> 32));
          pj = expf(xv / st - ml) / Sp;
        }
        cum += pj;
        float ex = cum - pj;
        if (ex < topp) jp = j;
      }
      float thr;
      if (jp < ck && jp < Cact) {
        u64t kj = sortedFull ? keyA[jp] : sel[jp];
        float xv = fkeyInv((unsigned int)(kj >> 32));
        thr = xv / st;
      } else thr = -INFINITY;
      sh_thresh = thr;
    }
    __syncthreads();
    const float thr = sh_thresh;
    float bm = -INFINITY; int bi = 0x7fffffff;
    for (int j = tid; j < Cact; j += TPB) {
      u64t ka = keyA[j];
      float xv = fkeyInv((unsigned int)(ka >> 32));
      int gi = (int)(ka & 0xffffffffu);
      float l = xv / st;
      float e = expf(l - ml);
      if (keepTest(e) && l >= thr) {
        float uv = uu[gi];
        float g = -logf(-logf(uv));
        float val = l + g;
        if (val > bm || (val == bm && gi < bi)) { bm = val; bi = gi; }
      }
    }
    blockArgMaxF(bm, bi, sredF, sredI);
    sampled = bi;
  } else {
    // deep: mass combine (+band) -> scan -> (bp, seed); collect/sort/thr in kD
    if (!bandOv) {
      if (tid < MBINS) {
        u64t m = 0;
        for (int w = 0; w < NS; ++w) m += mass[((size_t)row * NS + w) * MBINS + tid];
        int bc = sh_bCnt;
        for (int j = 0; j < bc; ++j) if (sh_bBin[j] == tid) m += sh_bMass[j];
        keyA[tid] = m;
      }
    } else {
      for (int b = tid; b < MBINS; b += TPB) keyA[b] = 0ull;
      __syncthreads();
      auto bodyM = [&](float vv) {
        float l = vv / st; float e = expf(l - ml);
        if (keepTest(e)) {
          float fm = (m0 - vv) * scaleM;
          if (fm < (float)MBINS) atomicAdd(&keyA[(int)fm], (u64t)((double)e * 4294967296.0));
        }
      };
      for (int i4 = tid; i4 < V4; i4 += TPB) { float4 v = x4[i4]; bodyM(v.x); bodyM(v.y); bodyM(v.z); bodyM(v.w); }
      for (int i = (V4 << 2) + tid; i < V; i += TPB) bodyM(x[i]);
    }
    __syncthreads();
    u64t mh = (tid < MBINS) ? keyA[tid] : 0ull;
    for (int off = 1; off < MBINS; off <<= 1) {
      u64t add = (tid < MBINS && tid >= off) ? keyA[tid - off] : 0ull;
      __syncthreads();
      if (tid < MBINS) keyA[tid] += add;
      __syncthreads();
    }
    const double TP = (double)topp * (double)Sp;
    int q = -1; u64t myexcl = 0;
    if (tid < MBINS && mh > 0ull) {
      u64t excl = keyA[tid] - mh;
      if ((double)excl * (1.0 / 4294967296.0) < TP) { q = tid; myexcl = excl; }
    }
    int bp = blockMaxI(q, sredI);
    if (bp >= 0 && tid == bp) sh_seed = (double)myexcl * (1.0 / 4294967296.0);
    if (bp < 0 && tid == 0) sh_seed = 0.0;
    __syncthreads();
    if (tid == 0) {
      w_bpM[row] = bp;
      w_seed[row] = sh_seed;
      w_spD[row] = Sp;
      if (bp < 0) w_thr[row] = -INFINITY;
    }
  }

  // ----- token logprob + rank (non-deep only) -----
  if (!deep) {
    if (tid == 0) sh_toklp = (x[sampled] - m0) - logS0;
    __syncthreads();
    const float toklp = sh_toklp;
    int rc = 0;
    for (int j = tid; j < Cact; j += TPB) {
      float xv = fkeyInv((unsigned int)(keyA[j] >> 32));
      float lp = (xv - m0) - logS0;
      if (lp >= toklp) rc++;
    }
    int rank = blockSumI(rc, sredI);
    float* o_samp = out;
    float* o_idx  = out + T;
    float* o_lps  = out + T + (size_t)T * (NL + 1);
    float* o_rank = out + T + (size_t)2 * T * (NL + 1);
    if (tid == 0) {
      o_samp[row] = (float)sampled;
      o_idx[(size_t)row * (NL + 1)] = (float)sampled;
      o_lps[(size_t)row * (NL + 1)] = toklp;
      o_rank[row] = (float)rank;
    }
  }
}

// =================== KD: deep-row crossing-bin collect + sort + thr ===================
__global__ __launch_bounds__(TPB) void kD_thr(const float* __restrict__ logits,
    const float* __restrict__ temp_arr, const float* __restrict__ minp_arr,
    const float* __restrict__ topp_arr, const int* __restrict__ topk_arr,
    const u64t* __restrict__ maxes, const float* __restrict__ sl_ws,
    const int* __restrict__ w_bpM, const float* __restrict__ w_spD,
    const double* __restrict__ w_seed, float* __restrict__ w_thr, int V) {
  const int row = blockIdx.x, tid = threadIdx.x;
  const float temp = temp_arr[row];
  if (temp < 1e-5f || topk_arr[row] > 0) return;
  const int bp = w_bpM[row];
  if (bp < 0) return;
  __shared__ u64t keyA[CAP];
  __shared__ float pvals[CAP];
  __shared__ u64t smax[NS];
  __shared__ float ssl[NS];
  __shared__ int sh_cnt;
  if (tid < NS) { smax[tid] = maxes[row * NS + tid]; ssl[tid] = sl_ws[row * NS + tid]; }
  if (tid == 0) sh_cnt = 0;
  __syncthreads();
  u64t mk = smax[0];
  for (int w = 1; w < NS; ++w) { u64t t = smax[w]; if (t > mk) mk = t; }
  float S = ssl[0];
  for (int w = 1; w < NS; ++w) S += ssl[w];
  const float m0 = ordInv((unsigned int)(mk >> 32));
  const float st = temp;
  const float ml = m0 / st;
  const float minp = minp_arr[row];
  const float rhs = minp * (1.0f / S);
  const float rhsS = rhs * S;
  const float rhsHi = rhsS * (1.0f + 1e-6f);
  const float rhsLo = rhsS * (1.0f - 1e-6f);
  auto keepTest = [&](float e) -> bool {
    if (e > rhsHi) return true;
    if (e < rhsLo) return false;
    return (e / S) >= rhs;
  };
  const float scaleM = (float)MBINS / MWIN;
  const float* x = logits + (size_t)row * V;
  const int V4 = V >> 2;
  const float4* x4 = (const float4*)x;
  auto body = [&](float vv, int gi) {
    float fm = (m0 - vv) * scaleM;
    if (fm < (float)MBINS && (int)fm == bp) {
      float l = vv / st;
      float e = expf(l - ml);
      if (keepTest(e)) {
        int pos = atomicAdd(&sh_cnt, 1);
        if (pos < CAP) keyA[pos] = ((u64t)fkeyDesc(vv) << 32) | (unsigned int)gi;
      }
    }
  };
  for (int i4 = tid; i4 < V4; i4 += TPB) {
    float4 v = x4[i4]; int b = i4 << 2;
    body(v.x, b); body(v.y, b + 1); body(v.z, b + 2); body(v.w, b + 3);
  }
  for (int i = (V4 << 2) + tid; i < V; i += TPB) body(x[i], i);
  __syncthreads();
  int C5 = sh_cnt < CAP ? sh_cnt : CAP;
  if (C5 <= 1024) {
    u64t kc = (tid < C5) ? keyA[tid] : ~0ull;
    bitonicReg1024(kc, keyA);
  } else {
    int n5 = 128; while (n5 < C5) n5 <<= 1;
    for (int i = C5 + tid; i < n5; i += TPB) keyA[i] = ~0ull;
    __syncthreads();
    bitonicSortN(keyA, n5);
  }
  const float Sp = w_spD[row];
  for (int j = tid; j < C5; j += TPB) {
    float xv = fkeyInv((unsigned int)(keyA[j] >> 32));
    pvals[j] = expf(xv / st - ml) / Sp;
  }
  __syncthreads();
  if (tid == 0) {
    const float topp = topp_arr[row];
    float cum = (float)(w_seed[row] / (double)Sp);
    float lastVal = fkeyInv((unsigned int)(keyA[0] >> 32));
    for (int j = 0; j < C5; ++j) {
      float pj = pvals[j];
      cum += pj;
      float ex = cum - pj;
      if (ex < topp) lastVal = fkeyInv((unsigned int)(keyA[j] >> 32));
    }
    w_thr[row] = lastVal / st;
  }
}

// =================== K6: sliced Gumbel argmax for deep rows ===================
__global__ __launch_bounds__(TPBS) void k6_gumbel(const float* __restrict__ logits,
    const float* __restrict__ temp_arr, const float* __restrict__ minp_arr,
    const int* __restrict__ topk_arr, const float* __restrict__ u_arr,
    const u64t* __restrict__ maxes, const float* __restrict__ sl_ws,
    const float* __restrict__ w_thr, u64t* __restrict__ gkey, int V) {
  const int row = blockIdx.y, s = blockIdx.x, tid = threadIdx.x;
  const float temp = temp_arr[row];
  if (temp < 1e-5f || topk_arr[row] > 0) return;
  __shared__ u64t smax[NS];
  __shared__ float ssl[NS];
  __shared__ float sredF[16];
  __shared__ int sredI[16];
  if (tid < NS) { smax[tid] = maxes[row * NS + tid]; ssl[tid] = sl_ws[row * NS + tid]; }
  __syncthreads();
  u64t mk = smax[0];
  for (int w = 1; w < NS; ++w) { u64t t = smax[w]; if (t > mk) mk = t; }
  float S = ssl[0];
  for (int w = 1; w < NS; ++w) S += ssl[w];
  const float m0 = ordInv((unsigned int)(mk >> 32));
  const float st = temp;
  const float ml = m0 / st;
  const float minp = minp_arr[row];
  const float rhs = minp * (1.0f / S);
  const float rhsS = rhs * S;
  const float rhsHi = rhsS * (1.0f + 1e-6f);
  const float rhsLo = rhsS * (1.0f - 1e-6f);
  auto keepTest = [&](float e) -> bool {
    if (e > rhsHi) return true;
    if (e < rhsLo) return false;
    return (e / S) >= rhs;
  };
  const float thr = w_thr[row];
  const float* x  = logits + (size_t)row * V;
  const float* uu = u_arr  + (size_t)row * V;
  const int V4 = V >> 2;
  const float4* x4 = (const float4*)x;
  const float4* u4 = (const float4*)uu;
  const int a4 = (int)(((long long)V4 * s) / NS), b4 = (int)(((long long)V4 * (s + 1)) / NS);
  float bm = -INFINITY; int bi = 0x7fffffff;
  auto body = [&](float vv, float uv, int gi) {
    float l = vv / st;
    float e = expf(l - ml);
    if (keepTest(e) && l >= thr) {
      float g = -logf(-logf(uv));
      float val = l + g;
      if (val > bm || (val == bm && gi < bi)) { bm = val; bi = gi; }
    }
  };
  for (int i4 = a4 + tid; i4 < b4; i4 += TPBS) {
    float4 v = x4[i4]; float4 w = u4[i4]; int b = i4 << 2;
    body(v.x, w.x, b); body(v.y, w.y, b + 1); body(v.z, w.z, b + 2); body(v.w, w.w, b + 3);
  }
  if (s == NS - 1) for (int i = (V4 << 2) + tid; i < V; i += TPBS) body(x[i], uu[i], i);
  blockArgMaxF(bm, bi, sredF, sredI);
  if (tid == 0) gkey[row * NS + s] = mkMaxKey(bm, bi);
}

// =================== K7: deep-row finalize ===================
__global__ __launch_bounds__(TPB) void k7_deepfin(const float* __restrict__ logits,
    const float* __restrict__ temp_arr, const int* __restrict__ topk_arr,
    const u64t* __restrict__ gkey, const float* __restrict__ s0_ws,
    const u64t* __restrict__ maxes, float* __restrict__ out, int T, int V, int NL) {
  const int row = blockIdx.x, tid = threadIdx.x;
  const float temp = temp_arr[row];
  if (temp < 1e-5f || topk_arr[row] > 0) return;
  __shared__ u64t sg[NS];
  __shared__ u64t smax[NS];
  __shared__ float sp0[NS];
  __shared__ int sredI[16];
  if (tid < NS) { sg[tid] = gkey[row * NS + tid]; smax[tid] = maxes[row * NS + tid]; sp0[tid] = s0_ws[row * NS + tid]; }
  __syncthreads();
  u64t gk = sg[0];
  for (int w = 1; w < NS; ++w) { if (sg[w] > gk) gk = sg[w]; }
  u64t mk = smax[0];
  for (int w = 1; w < NS; ++w) { u64t t = smax[w]; if (t > mk) mk = t; }
  const float m0 = ordInv((unsigned int)(mk >> 32));
  const float S0 = combineS0(smax, sp0, m0);
  const float logS0 = logf(S0);
  const int sampled = (int)(~(unsigned int)gk);
  const float* x = logits + (size_t)row * V;
  const float toklp = (x[sampled] - m0) - logS0;
  const int V4 = V >> 2;
  const float4* x4 = (const float4*)x;
  int rc = 0;
  auto body = [&](float vv) {
    float lp = (vv - m0) - logS0;
    if (lp >= toklp) rc++;
  };
  for (int i4 = tid; i4 < V4; i4 += TPB) { float4 v = x4[i4]; body(v.x); body(v.y); body(v.z); body(v.w); }
  for (int i = (V4 << 2) + tid; i < V; i += TPB) body(x[i]);
  int rank = blockSumI(rc, sredI);
  float* o_samp = out;
  float* o_idx  = out + T;
  float* o_lps  = out + T + (size_t)T * (NL + 1);
  float* o_rank = out + T + (size_t)2 * T * (NL + 1);
  if (tid == 0) {
    o_samp[row] = (float)sampled;
    o_idx[(size_t)row * (NL + 1)] = (float)sampled;
    o_lps[(size_t)row * (NL + 1)] = toklp;
    o_rank[row] = (float)rank;
  }
}

// =================== monolithic fallback (used if ws too small) ===================
__global__ __launch_bounds__(TPB) void sampler_mono(
    const float* __restrict__ logits, const float* __restrict__ temp_arr,
    const float* __restrict__ minp_arr, const float* __restrict__ topp_arr,
    const int* __restrict__ topk_arr, const float* __restrict__ u_arr,
    float* __restrict__ out, int T, int V, int NL) {
  __shared__ u64t keyA[CAP];
  __shared__ u64t keyB[CAP];
  __shared__ float pvals[CAP];
  __shared__ int   cnthist[NBINS];
  __shared__ u64t  masshist[NBINS];
  __shared__ float sredF[16];
  __shared__ int   sredI[16];
  __shared__ float sh_thresh, sh_toklp, sh_Rm, sh_Roff;
  __shared__ double sh_seedD, sh_seedBase;
  __shared__ int sh_B64, sh_Bp, sh_cnt, sh_state;

  const int row = blockIdx.x;
  const int tid = threadIdx.x;
  const float* x  = logits + (size_t)row * V;
  const float* uu = u_arr  + (size_t)row * V;
  const float temp = temp_arr[row];
  const float minp = minp_arr[row];
  const float topp = topp_arr[row];
  const int   topk = topk_arr[row];
  const bool greedy = (temp < 1e-5f);
  const float st = greedy ? 1.0f : temp;
  const int V4 = V >> 2;
  const float4* x4 = (const float4*)x;

  float m0; int gidx;
  {
    float lm = -INFINITY; int lidx = 0x7fffffff;
    for (int i4 = tid; i4 < V4; i4 += TPB) {
      float4 v = x4[i4]; int b = i4 << 2;
      if (v.x > lm) { lm = v.x; lidx = b; }
      if (v.y > lm) { lm = v.y; lidx = b + 1; }
      if (v.z > lm) { lm = v.z; lidx = b + 2; }
      if (v.w > lm) { lm = v.w; lidx = b + 3; }
    }
    for (int i = (V4 << 2) + tid; i < V; i += TPB) {
      float v = x[i]; if (v > lm) { lm = v; lidx = i; }
    }
    blockArgMaxF(lm, lidx, sredF, sredI);
    m0 = lm; gidx = lidx;
  }
  const float ml = m0 / st;

  float Rcur = 2.0f;
  float binScale = (float)NBINS / Rcur;
  for (int b = tid; b < NBINS; b += TPB) cnthist[b] = 0;
  __syncthreads();
  float S0, S;
  {
    float s0p = 0.f, slp = 0.f;
    auto histAdd = [&](float vv) {
      float fb = (m0 - vv) * binScale;
      if (fb < (float)NBINS) atomicAdd(&cnthist[(int)fb], 1);
    };
    for (int i4 = tid; i4 < V4; i4 += TPB) {
      float4 v = x4[i4];
      s0p += expf(v.x - m0) + expf(v.y - m0) + expf(v.z - m0) + expf(v.w - m0);
      if (!greedy) slp += expf(v.x / st - ml) + expf(v.y / st - ml) + expf(v.z / st - ml) + expf(v.w / st - ml);
      histAdd(v.x); histAdd(v.y); histAdd(v.z); histAdd(v.w);
    }
    for (int i = (V4 << 2) + tid; i < V; i += TPB) {
      float v = x[i]; s0p += expf(v - m0); if (!greedy) slp += expf(v / st - ml); histAdd(v);
    }
    S0 = blockSumF(s0p, sredF);
    S = greedy ? S0 : blockSumF(slp, sredF);
  }

  int need = NSEL;
  if (topk > need) need = topk;
  if (need > CAP / 2) need = CAP / 2;
  if (need > V) need = V;
  int B64;
  for (int attempt = 0; ; ++attempt) {
    __syncthreads();
    if (tid == 0) {
      long long cum = 0; int b64 = -1; long long c64 = 0;
      for (int b = 0; b < NBINS; ++b) {
        cum += cnthist[b];
        if (cum >= need) { b64 = b; c64 = cum; break; }
      }
      int state;
      if (b64 >= 0 && c64 <= CAP) state = 1;
      else if (b64 < 0) state = 0;
      else state = 2;
      if (attempt >= 3 && state != 1) { state = 1; if (b64 < 0) b64 = NBINS - 1; }
      sh_state = state; sh_B64 = b64;
    }
    __syncthreads();
    if (sh_state == 1) { B64 = sh_B64; break; }
    Rcur = (sh_state == 0) ? Rcur * 8.0f : Rcur * 0.125f;
    binScale = (float)NBINS / Rcur;
    __syncthreads();
    for (int b = tid; b < NBINS; b += TPB) cnthist[b] = 0;
    __syncthreads();
    auto histAdd2 = [&](float vv) {
      float fb = (m0 - vv) * binScale;
      if (fb < (float)NBINS) atomicAdd(&cnthist[(int)fb], 1);
    };
    for (int i4 = tid; i4 < V4; i4 += TPB) {
      float4 v = x4[i4];
      histAdd2(v.x); histAdd2(v.y); histAdd2(v.z); histAdd2(v.w);
    }
    for (int i = (V4 << 2) + tid; i < V; i += TPB) histAdd2(x[i]);
  }

  const float logS0 = logf(S0);
  const float rhs = minp * (1.0f / S);
  const float rhsS = rhs * S;
  const float rhsHi = rhsS * (1.0f + 1e-6f);
  const float rhsLo = rhsS * (1.0f - 1e-6f);
  auto keepTest = [&](float e) -> bool {
    if (e > rhsHi) return true;
    if (e < rhsLo) return false;
    return (e / S) >= rhs;
  };
  const bool needMass = (!greedy && topk <= 0);
  const float scaleM0 = (float)NBINS / 16.0f;

  for (int b = tid; b < NBINS; b += TPB) { cnthist[b] = 0; masshist[b] = 0ull; }
  if (tid == 0) { sh_cnt = 0; sh_Rm = 16.0f; sh_Roff = 0.0f; sh_seedBase = 0.0; }
  __syncthreads();
  float Sp; int ck;
  {
    float spp = 0.f; int ckp = 0;
    auto bodyB = [&](float vv, int gi) {
      float fb = (m0 - vv) * binScale;
      if (fb < (float)NBINS && (int)fb <= B64) {
        int pos = atomicAdd(&sh_cnt, 1);
        if (pos < CAP) keyA[pos] = ((u64t)fkeyDesc(vv) << 32) | (unsigned int)gi;
      }
      if (!greedy) {
        float l = vv / st;
        float e = expf(l - ml);
        if (keepTest(e)) {
          spp += e; ckp++;
          if (needMass) {
            float fm = (m0 - vv) * scaleM0;
            if (fm < (float)NBINS) {
              int bm = (int)fm;
              atomicAdd(&masshist[bm], (u64t)((double)e * 4294967296.0));
              atomicAdd(&cnthist[bm], 1);
            }
          }
        }
      }
    };
    for (int i4 = tid; i4 < V4; i4 += TPB) {
      float4 v = x4[i4]; int b = i4 << 2;
      bodyB(v.x, b); bodyB(v.y, b + 1); bodyB(v.z, b + 2); bodyB(v.w, b + 3);
    }
    for (int i = (V4 << 2) + tid; i < V; i += TPB) bodyB(x[i], i);
    Sp = blockSumF(spp, sredF);
    ck = blockSumI(ckp, sredI);
  }
  int Cact = sh_cnt; if (Cact > CAP) Cact = CAP;

  int n = 128; while (n < Cact) n <<= 1;
  for (int i = Cact + tid; i < n; i += TPB) keyA[i] = ~0ull;
  __syncthreads();
  bitonicSortN(keyA, n);
  for (int j = tid; j < n; j += TPB) {
    if (j < Cact) {
      u64t ka = keyA[j];
      float xv = fkeyInv((unsigned int)(ka >> 32));
      float lp = (xv - m0) - logS0;
      keyB[j] = ((u64t)fkeyDesc(lp) << 32) | (ka & 0xffffffffu);
    } else keyB[j] = ~0ull;
  }
  bitonicSortN(keyB, n);

  int sampled;
  if (greedy) {
    sampled = gidx;
  } else if (topk > 0) {
    if (tid == 0) {
      int k = topk; if (k > V) k = V; if (k > CAP) k = CAP;
      int jp = 0; float cum = 0.f;
      for (int j = 0; j < k; ++j) {
        float pj = 0.f;
        if (j < ck && j < Cact) {
          float xv = fkeyInv((unsigned int)(keyA[j] >> 32));
          pj = expf(xv / st - ml) / Sp;
        }
        cum += pj;
        float ex = cum - pj;
        if (ex < topp) jp = j;
      }
      float thr;
      if (jp < ck && jp < Cact) {
        float xv = fkeyInv((unsigned int)(keyA[jp] >> 32));
        thr = xv / st;
      } else thr = -INFINITY;
      sh_thresh = thr;
    }
    __syncthreads();
    const float thr = sh_thresh;
    float bm = -INFINITY; int bi = 0x7fffffff;
    for (int j = tid; j < Cact; j += TPB) {
      u64t ka = keyA[j];
      float xv = fkeyInv((unsigned int)(ka >> 32));
      int gi = (int)(ka & 0xffffffffu);
      float l = xv / st;
      float e = expf(l - ml);
      if (keepTest(e) && l >= thr) {
        float uv = uu[gi];
        float g = -logf(-logf(uv));
        float val = l + g;
        if (val > bm || (val == bm && gi < bi)) { bm = val; bi = gi; }
      }
    }
    blockArgMaxF(bm, bi, sredF, sredI);
    sampled = bi;
  } else {
    for (int attempt = 0; ; ++attempt) {
      __syncthreads();
      if (tid == 0) {
        float Rm = sh_Rm, Roff = sh_Roff;
        double TP = (double)topp * (double)Sp;
        double cm = sh_seedBase; int bp = -1; double seed = sh_seedBase; int cbp = 0;
        for (int b = 0; b < NBINS; ++b) {
          u64t mh = masshist[b];
          if (mh > 0ull && cm < TP) { bp = b; seed = cm; cbp = cnthist[b]; }
          cm += (double)mh * (1.0 / 4294967296.0);
        }
        int state = 1;
        if (attempt < 3) {
          if (cm < TP && Roff == 0.0f) {
            state = 0; sh_Rm = Rm * 8.0f;
          } else if (bp >= 0 && cbp > CAP) {
            state = 2;
            float bw = Rm / (float)NBINS;
            sh_Roff = Roff + (float)bp * bw;
            sh_Rm = bw;
            sh_seedBase = seed;
          }
        }
        if (bp < 0) { bp = 0; seed = sh_seedBase; }
        sh_Bp = bp; sh_seedD = seed; sh_state = state;
      }
      __syncthreads();
      if (sh_state == 1) break;
      float Rm = sh_Rm, Roff = sh_Roff;
      float sM = (float)NBINS / Rm;
      for (int b = tid; b < NBINS; b += TPB) { cnthist[b] = 0; masshist[b] = 0ull; }
      __syncthreads();
      auto bodyM = [&](float vv) {
        float fm = ((m0 - vv) - Roff) * sM;
        if (fm >= 0.f && fm < (float)NBINS) {
          float l = vv / st;
          float e = expf(l - ml);
          if (keepTest(e)) {
            int bm = (int)fm;
            atomicAdd(&masshist[bm], (u64t)((double)e * 4294967296.0));
            atomicAdd(&cnthist[bm], 1);
          }
        }
      };
      for (int i4 = tid; i4 < V4; i4 += TPB) {
        float4 v = x4[i4]; bodyM(v.x); bodyM(v.y); bodyM(v.z); bodyM(v.w);
      }
      for (int i = (V4 << 2) + tid; i < V; i += TPB) bodyM(x[i]);
    }
    const int Bp = sh_Bp;
    const float RmF = sh_Rm, RoffF = sh_Roff;
    const float sM = (float)NBINS / RmF;
    if (tid == 0) sh_cnt = 0;
    __syncthreads();
    auto bodyC = [&](float vv, int gi) {
      float fm = ((m0 - vv) - RoffF) * sM;
      if (fm >= 0.f && fm < (float)NBINS && (int)fm == Bp) {
        float l = vv / st;
        float e = expf(l - ml);
        if (keepTest(e)) {
          int pos = atomicAdd(&sh_cnt, 1);
          if (pos < CAP) keyA[pos] = ((u64t)fkeyDesc(vv) << 32) | (unsigned int)gi;
        }
      }
    };
    for (int i4 = tid; i4 < V4; i4 += TPB) {
      float4 v = x4[i4]; int b = i4 << 2;
      bodyC(v.x, b); bodyC(v.y, b + 1); bodyC(v.z, b + 2); bodyC(v.w, b + 3);
    }
    for (int i = (V4 << 2) + tid; i < V; i += TPB) bodyC(x[i], i);
    __syncthreads();
    int C5 = sh_cnt; if (C5 > CAP) C5 = CAP;
    int n5 = 128; while (n5 < C5) n5 <<= 1;
    for (int i = C5 + tid; i < n5; i += TPB) keyA[i] = ~0ull;
    __syncthreads();
    bitonicSortN(keyA, n5);
    for (int j = tid; j < C5; j += TPB) {
      float xv = fkeyInv((unsigned int)(keyA[j] >> 32));
      pvals[j] = expf(xv / st - ml) / Sp;
    }
    __syncthreads();
    if (tid == 0) {
      float cum = (float)(sh_seedD / (double)Sp);
      float lastVal = fkeyInv((unsigned int)(keyA[0] >> 32));
      for (int j = 0; j < C5; ++j) {
        float pj = pvals[j];
        cum += pj;
        float ex = cum - pj;
        if (ex < topp) lastVal = fkeyInv((unsigned int)(keyA[j] >> 32));
      }
      sh_thresh = lastVal / st;
    }
    __syncthreads();
    const float thr = sh_thresh;
    const float4* u4 = (const float4*)uu;
    float bm = -INFINITY; int bi = 0x7fffffff;
    auto body6 = [&](float vv, float uv, int gi) {
      float l = vv / st;
      float e = expf(l - ml);
      if (keepTest(e) && l >= thr) {
        float g = -logf(-logf(uv));
        float val = l + g;
        if (val > bm || (val == bm && gi < bi)) { bm = val; bi = gi; }
      }
    };
    for (int i4 = tid; i4 < V4; i4 += TPB) {
      float4 v = x4[i4]; float4 w = u4[i4]; int b = i4 << 2;
      body6(v.x, w.x, b); body6(v.y, w.y, b + 1); body6(v.z, w.z, b + 2); body6(v.w, w.w, b + 3);
    }
    for (int i = (V4 << 2) + tid; i < V; i += TPB) body6(x[i], uu[i], i);
    blockArgMaxF(bm, bi, sredF, sredI);
    sampled = bi;
  }

  if (tid == 0) sh_toklp = (x[sampled] - m0) - logS0;
  __syncthreads();
  const float toklp = sh_toklp;
  int rank;
  {
    int rc = 0;
    if (!needMass) {
      for (int j = tid; j < Cact; j += TPB) {
        float xv = fkeyInv((unsigned int)(keyA[j] >> 32));
        float lp = (xv - m0) - logS0;
        if (lp >= toklp) rc++;
      }
    } else {
      auto body7 = [&](float vv) {
        float lp = (vv - m0) - logS0;
        if (lp >= toklp) rc++;
      };
      for (int i4 = tid; i4 < V4; i4 += TPB) {
        float4 v = x4[i4]; body7(v.x); body7(v.y); body7(v.z); body7(v.w);
      }
      for (int i = (V4 << 2) + tid; i < V; i += TPB) body7(x[i]);
    }
    rank = blockSumI(rc, sredI);
  }

  float* o_samp = out;
  float* o_idx  = out + T;
  float* o_lps  = out + T + (size_t)T * (NL + 1);
  float* o_rank = out + T + (size_t)2 * T * (NL + 1);
  if (tid == 0) {
    o_samp[row] = (float)sampled;
    o_idx[(size_t)row * (NL + 1)] = (float)sampled;
    o_lps[(size_t)row * (NL + 1)] = toklp;
    o_rank[row] = (float)rank;
  }
  for (int j = tid; j < NL; j += TPB) {
    u64t kb = keyB[j];
    o_idx[(size_t)row * (NL + 1) + 1 + j] = (float)(unsigned int)(kb & 0xffffffffu);
    o_lps[(size_t)row * (NL + 1) + 1 + j] = fkeyInv((unsigned int)(kb >> 32));
  }
}

extern "C" void kernel_launch(void* const* d_in, const int* in_sizes, int n_in,
                              void* d_out, int out_size, void* d_ws, size_t ws_size,
                              hipStream_t stream) {
  const float* logits = (const float*)d_in[0];
  const float* temp   = (const float*)d_in[1];
  const float* minp   = (const float*)d_in[2];
  const float* topp   = (const float*)d_in[3];
  const int*   topk   = (const int*)d_in[4];
  const float* u      = (const float*)d_in[5];
  const int T  = in_sizes[1];
  const int V  = in_sizes[0] / T;
  const int NL = (out_size / T - 4) / 2;

  // ws layout (8-byte entries first)
  size_t off = 0;
  char* base = (char*)d_ws;
  u64t*   w_maxes   = (u64t*)(base + off);   off += (size_t)T * NS * 8;
  u64t*   w_cand    = (u64t*)(base + off);   off += (size_t)T * CAP * 8;
  u64t*   w_mass    = (u64t*)(base + off);   off += (size_t)T * NS * MBINS * 8;  // per-slice
  u64t*   w_gkey    = (u64t*)(base + off);   off += (size_t)T * NS * 8;
  u64t*   w_band    = (u64t*)(base + off);   off += (size_t)T * BANDCAP * 8;
  double* w_seed    = (double*)(base + off); off += (size_t)T * 8;
  float*  w_s0      = (float*)(base + off);  off += (size_t)T * NS * 4;
  float*  w_sl      = (float*)(base + off);  off += (size_t)T * NS * 4;
  float*  w_sp      = (float*)(base + off);  off += (size_t)T * NS * 4;
  int*    w_ck      = (int*)(base + off);    off += (size_t)T * NS * 4;
  int*    w_ccnt    = (int*)(base + off);    off += (size_t)T * 4;
  int*    w_bandcnt = (int*)(base + off);    off += (size_t)T * 4;
  float*  w_thr     = (float*)(base + off);  off += (size_t)T * 4;
  int*    w_bpM     = (int*)(base + off);    off += (size_t)T * 4;
  float*  w_spD     = (float*)(base + off);  off += (size_t)T * 4;

  if (off > ws_size) {
    sampler_mono<<<T, TPB, 0, stream>>>(logits, temp, minp, topp, topk, u,
                                        (float*)d_out, T, V, NL);
    return;
  }

  dim3 gS(NS, T);
  k1_max<<<gS, TPBS, 0, stream>>>(logits, w_maxes, w_s0, w_ccnt, w_bandcnt, V);
  k2_all<<<gS, TPBS, 0, stream>>>(logits, temp, minp, topk, w_maxes, w_sl,
                                  w_sp, w_ck, w_ccnt, w_cand, w_bandcnt, w_band,
                                  w_mass, V);
  k5_final<<<T, TPB, 0, stream>>>(logits, temp, minp, topp, topk, u, w_maxes,
                                  w_s0, w_sl, w_sp, w_ck, w_ccnt, w_cand, w_mass,
                                  w_band, w_bandcnt, w_thr, w_bpM, w_seed, w_spD,
                                  (float*)d_out, T, V, NL);
  kD_thr<<<T, TPB, 0, stream>>>(logits, temp, minp, topp, topk, w_maxes, w_sl,
                                w_bpM, w_spD, w_seed, w_thr, V);
  k6_gumbel<<<gS, TPBS, 0, stream>>>(logits, temp, minp, topk, u, w_maxes, w_sl,
                                     w_thr, w_gkey, V);
  k7_deepfin<<<T, TPB, 0, stream>>>(logits, temp, topk, w_gkey, w_s0, w_maxes,
                                    (float*)d_out, T, V, NL);
}

// Round 12
// 210.867 us; speedup vs baseline: 1.2718x; 1.2718x over previous
//
#include <hip/hip_runtime.h>
#include <math.h>

#define TPB 1024      // finalize threads
#define TPBS 256      // streaming kernel threads
#define NS 8          // slices per row
#define NBINS 512     // fallback hist bins
#define CAP 2048
#define NSEL 64
#define MBINS 1024    // deep-row mass hist bins
#define MWIN 16.0f
#define WIN 2.0f      // candidate collect window below max
#define SLCAP 1024    // per-block LDS candidate staging capacity
#define BANDCAP 64    // deferred min-p band elements per row

typedef unsigned long long u64t;

// ---------- key encodings ----------
__device__ __forceinline__ unsigned int ordAsc(float v) {
  unsigned int b = __float_as_uint(v);
  return (b & 0x80000000u) ? ~b : (b | 0x80000000u);
}
__device__ __forceinline__ float ordInv(unsigned int o) {
  return __uint_as_float((o & 0x80000000u) ? (o & 0x7fffffffu) : ~o);
}
__device__ __forceinline__ unsigned int fkeyDesc(float v) { return ~ordAsc(v); }
__device__ __forceinline__ float fkeyInv(unsigned int kd) { return ordInv(~kd); }
// max-key: larger value wins; tie -> smaller index wins
__device__ __forceinline__ u64t mkMaxKey(float v, int idx) {
  return ((u64t)ordAsc(v) << 32) | (unsigned int)(~(unsigned int)idx);
}

// ---------- block reductions ----------
__device__ __forceinline__ float blockSumF(float v, float* sred) {
  #pragma unroll
  for (int o = 32; o > 0; o >>= 1) v += __shfl_down(v, o, 64);
  int wid = threadIdx.x >> 6, lane = threadIdx.x & 63, nw = blockDim.x >> 6;
  __syncthreads();
  if (lane == 0) sred[wid] = v;
  __syncthreads();
  if (threadIdx.x == 0) { float r = sred[0]; for (int w = 1; w < nw; ++w) r += sred[w]; sred[0] = r; }
  __syncthreads();
  float r = sred[0];
  __syncthreads();
  return r;
}
__device__ __forceinline__ int blockSumI(int v, int* sred) {
  #pragma unroll
  for (int o = 32; o > 0; o >>= 1) v += __shfl_down(v, o, 64);
  int wid = threadIdx.x >> 6, lane = threadIdx.x & 63, nw = blockDim.x >> 6;
  __syncthreads();
  if (lane == 0) sred[wid] = v;
  __syncthreads();
  if (threadIdx.x == 0) { int r = sred[0]; for (int w = 1; w < nw; ++w) r += sred[w]; sred[0] = r; }
  __syncthreads();
  int r = sred[0];
  __syncthreads();
  return r;
}
__device__ __forceinline__ int blockMaxI(int v, int* sred) {
  #pragma unroll
  for (int o = 32; o > 0; o >>= 1) { int v2 = __shfl_down(v, o, 64); if (v2 > v) v = v2; }
  int wid = threadIdx.x >> 6, lane = threadIdx.x & 63, nw = blockDim.x >> 6;
  __syncthreads();
  if (lane == 0) sred[wid] = v;
  __syncthreads();
  if (threadIdx.x == 0) { int r = sred[0]; for (int w = 1; w < nw; ++w) if (sred[w] > r) r = sred[w]; sred[0] = r; }
  __syncthreads();
  int r = sred[0];
  __syncthreads();
  return r;
}
__device__ __forceinline__ u64t blockMaxU64(u64t v, u64t* sred) {
  #pragma unroll
  for (int o = 32; o > 0; o >>= 1) { u64t v2 = __shfl_down(v, o, 64); if (v2 > v) v = v2; }
  int wid = threadIdx.x >> 6, lane = threadIdx.x & 63, nw = blockDim.x >> 6;
  __syncthreads();
  if (lane == 0) sred[wid] = v;
  __syncthreads();
  if (threadIdx.x == 0) { u64t r = sred[0]; for (int w = 1; w < nw; ++w) if (sred[w] > r) r = sred[w]; sred[0] = r; }
  __syncthreads();
  u64t r = sred[0];
  __syncthreads();
  return r;
}
__device__ __forceinline__ void blockArgMaxF(float& v, int& idx, float* sredf, int* sredi) {
  #pragma unroll
  for (int o = 32; o > 0; o >>= 1) {
    float v2 = __shfl_down(v, o, 64);
    int  i2 = __shfl_down(idx, o, 64);
    if (v2 > v || (v2 == v && i2 < idx)) { v = v2; idx = i2; }
  }
  int wid = threadIdx.x >> 6, lane = threadIdx.x & 63, nw = blockDim.x >> 6;
  __syncthreads();
  if (lane == 0) { sredf[wid] = v; sredi[wid] = idx; }
  __syncthreads();
  if (threadIdx.x == 0) {
    float bv = sredf[0]; int bi = sredi[0];
    for (int w = 1; w < nw; ++w) {
      float v2 = sredf[w]; int i2 = sredi[w];
      if (v2 > bv || (v2 == bv && i2 < bi)) { bv = v2; bi = i2; }
    }
    sredf[0] = bv; sredi[0] = bi;
  }
  __syncthreads();
  v = sredf[0]; idx = sredi[0];
  __syncthreads();
}

__device__ void bitonicSortN(u64t* keys, int n) {
  for (unsigned int k = 2; k <= (unsigned int)n; k <<= 1) {
    for (unsigned int j = k >> 1; j > 0; j >>= 1) {
      __syncthreads();
      for (unsigned int i = threadIdx.x; i < (unsigned int)n; i += blockDim.x) {
        unsigned int ixj = i ^ j;
        if (ixj > i) {
          u64t a = keys[i], b = keys[ixj];
          bool up = ((i & k) == 0);
          if ((a > b) == up) { keys[i] = b; keys[ixj] = a; }
        }
      }
    }
  }
  __syncthreads();
}

// hybrid register bitonic: n==1024, block must be 1024 threads.
__device__ u64t bitonicReg1024(u64t key, u64t* lds) {
  const int tid = threadIdx.x;
  for (unsigned int k = 2; k <= 1024; k <<= 1) {
    for (unsigned int j = k >> 1; j > 0; j >>= 1) {
      u64t partner;
      if (j >= 64) {
        __syncthreads();
        lds[tid] = key;
        __syncthreads();
        partner = lds[tid ^ j];
      } else {
        partner = __shfl_xor((unsigned long long)key, (int)j, 64);
      }
      bool up = ((tid & k) == 0);
      bool lower = ((tid & j) == 0);
      bool keepSmaller = (up == lower);
      bool pSmaller = (partner < key);
      if (keepSmaller == pSmaller) key = partner;
    }
  }
  __syncthreads();
  lds[tid] = key;
  __syncthreads();
  return key;
}

// combine rescaled S0 from per-slice (local-max) sums
__device__ __forceinline__ float combineS0(const u64t* smax, const float* s0s, float m0) {
  float S0 = 0.f;
  for (int w = 0; w < NS; ++w) {
    float ms = ordInv((unsigned int)(smax[w] >> 32));
    S0 += s0s[w] * expf(ms - m0);
  }
  return S0;
}

// =================== K1: single-pass slice max+argmax + online S0 sum ===================
__global__ __launch_bounds__(TPBS) void k1_max(const float* __restrict__ logits,
                                               u64t* __restrict__ maxes,
                                               float* __restrict__ s0_ws,
                                               int* __restrict__ ccnt,
                                               int* __restrict__ bandcnt, int V) {
  const int row = blockIdx.y, s = blockIdx.x, tid = threadIdx.x;
  if (s == 0 && tid == 0) { ccnt[row] = 0; bandcnt[row] = 0; }
  const float* x = logits + (size_t)row * V;
  const int V4 = V >> 2;
  const float4* x4 = (const float4*)x;
  const int a4 = (int)(((long long)V4 * s) / NS), b4 = (int)(((long long)V4 * (s + 1)) / NS);
  u64t best = 0ull;
  float mt = -INFINITY, s0 = 0.f;
  auto body = [&](float vv, int gi) {
    u64t k = mkMaxKey(vv, gi);
    if (k > best) best = k;
    if (vv > mt) { s0 = s0 * expf(mt - vv); mt = vv; }   // online rescale
    s0 += expf(vv - mt);
  };
  for (int i4 = a4 + tid; i4 < b4; i4 += TPBS) {
    float4 v = x4[i4]; int b = i4 << 2;
    body(v.x, b); body(v.y, b + 1); body(v.z, b + 2); body(v.w, b + 3);
  }
  if (s == NS - 1) for (int i = (V4 << 2) + tid; i < V; i += TPBS) body(x[i], i);
  __shared__ u64t sredU[16];
  __shared__ float sredF[16];
  best = blockMaxU64(best, sredU);
  if (tid == 0) maxes[row * NS + s] = best;
  // rescale thread-local sum to slice max, then reduce
  const float msv = ordInv((unsigned int)(best >> 32));
  float s0r = s0 * expf(mt - msv);    // mt=-inf (no elems) -> expf(-inf)=0 -> 0
  float r0 = blockSumF(s0r, sredF);
  if (tid == 0) s0_ws[row * NS + s] = r0;
}

// =================== K2: single streaming pass (S, Sp, ck, candidates, band, mass) ===================
__global__ __launch_bounds__(TPBS) void k2_all(const float* __restrict__ logits,
    const float* __restrict__ temp_arr, const float* __restrict__ minp_arr,
    const int* __restrict__ topk_arr, const u64t* __restrict__ maxes,
    float* __restrict__ sl_ws, float* __restrict__ sp_ws, int* __restrict__ ck_ws,
    int* __restrict__ ccnt, u64t* __restrict__ cand,
    int* __restrict__ bandcnt, u64t* __restrict__ band,
    u64t* __restrict__ mass, int V) {
  const int row = blockIdx.y, s = blockIdx.x, tid = threadIdx.x;
  __shared__ u64t smax[NS];
  __shared__ float sredF[16];
  __shared__ int sredI[16];
  __shared__ u64t lcand[SLCAP];
  __shared__ u64t lmass[MBINS];
  __shared__ int lcnt, lbase;
  const float temp = temp_arr[row];
  const bool greedy = (temp < 1e-5f);
  const int topk = topk_arr[row];
  const bool deep = (!greedy && topk <= 0);
  if (tid < NS) smax[tid] = maxes[row * NS + tid];
  if (tid == 0) lcnt = 0;
  if (deep) for (int b = tid; b < MBINS; b += TPBS) lmass[b] = 0ull;
  __syncthreads();
  u64t mk = smax[0];
  for (int w = 1; w < NS; ++w) { u64t t = smax[w]; if (t > mk) mk = t; }
  const float m0 = ordInv((unsigned int)(mk >> 32));
  const float wlo = m0 - WIN;
  const float* x = logits + (size_t)row * V;
  const int V4 = V >> 2;
  const float4* x4 = (const float4*)x;
  const int a4 = (int)(((long long)V4 * s) / NS), b4 = (int)(((long long)V4 * (s + 1)) / NS);

  if (greedy) {
    auto bodyG = [&](float vv, int gi) {
      if (vv >= wlo) {
        int pos = atomicAdd(&lcnt, 1);
        if (pos < SLCAP) lcand[pos] = ((u64t)fkeyDesc(vv) << 32) | (unsigned int)gi;
      }
    };
    for (int i4 = a4 + tid; i4 < b4; i4 += TPBS) {
      float4 v = x4[i4]; int b = i4 << 2;
      bodyG(v.x, b); bodyG(v.y, b + 1); bodyG(v.z, b + 2); bodyG(v.w, b + 3);
    }
    if (s == NS - 1) for (int i = (V4 << 2) + tid; i < V; i += TPBS) bodyG(x[i], i);
    __syncthreads();
    if (tid == 0) {
      sl_ws[row * NS + s] = 0.f; sp_ws[row * NS + s] = 0.f; ck_ws[row * NS + s] = 0;
      int c = lcnt;
      int add = (c > SLCAP) ? (c + CAP + 1) : c;
      lbase = atomicAdd(&ccnt[row], add);
    }
    __syncthreads();
    int c = lcnt < SLCAP ? lcnt : SLCAP;
    int base = lbase;
    for (int j = tid; j < c; j += TPBS) {
      int pos = base + j;
      if (pos < CAP) cand[(size_t)row * CAP + pos] = lcand[j];
    }
    return;
  }

  const float st = temp;
  const float ml = m0 / st;
  const float minp = minp_arr[row];
  const float bHi = minp * (1.0f + 4e-6f);
  const float bLo = minp * (1.0f - 4e-6f);
  const float scaleM = (float)MBINS / MWIN;
  float sl = 0.f, sp = 0.f; int ckp = 0;
  auto body = [&](float vv, int gi) {
    float l = vv / st;
    float e = expf(l - ml);
    sl += e;
    if (minp <= 0.f || e > bHi) {
      sp += e; ckp++;
      if (deep) {
        float fm = (m0 - vv) * scaleM;
        if (fm < (float)MBINS)
          atomicAdd(&lmass[(int)fm], (u64t)((double)e * 4294967296.0));
      }
    } else if (e >= bLo) {
      int pos = atomicAdd(&bandcnt[row], 1);
      if (pos < BANDCAP)
        band[(size_t)row * BANDCAP + pos] = ((u64t)(unsigned int)gi << 32) | __float_as_uint(vv);
    }
    if (vv >= wlo) {
      int pos = atomicAdd(&lcnt, 1);
      if (pos < SLCAP) lcand[pos] = ((u64t)fkeyDesc(vv) << 32) | (unsigned int)gi;
    }
  };
  for (int i4 = a4 + tid; i4 < b4; i4 += TPBS) {
    float4 v = x4[i4]; int b = i4 << 2;
    body(v.x, b); body(v.y, b + 1); body(v.z, b + 2); body(v.w, b + 3);
  }
  if (s == NS - 1) for (int i = (V4 << 2) + tid; i < V; i += TPBS) body(x[i], i);
  float rl = blockSumF(sl, sredF);
  float rp = blockSumF(sp, sredF);
  int rc = blockSumI(ckp, sredI);
  if (tid == 0) {
    sl_ws[row * NS + s] = rl; sp_ws[row * NS + s] = rp; ck_ws[row * NS + s] = rc;
    int c = lcnt;
    int add = (c > SLCAP) ? (c + CAP + 1) : c;
    lbase = atomicAdd(&ccnt[row], add);
  }
  __syncthreads();
  int c = lcnt < SLCAP ? lcnt : SLCAP;
  int base = lbase;
  for (int j = tid; j < c; j += TPBS) {
    int pos = base + j;
    if (pos < CAP) cand[(size_t)row * CAP + pos] = lcand[j];
  }
  if (deep) {
    u64t* mrow = mass + ((size_t)row * NS + s) * MBINS;
    for (int b = tid; b < MBINS; b += TPBS) mrow[b] = lmass[b];   // plain store, no zeroing needed
  }
}

// =================== K5: per-row finalize (non-deep complete; deep -> bp/seed) ===================
__global__ __launch_bounds__(TPB) void k5_final(const float* __restrict__ logits,
    const float* __restrict__ temp_arr, const float* __restrict__ minp_arr,
    const float* __restrict__ topp_arr, const int* __restrict__ topk_arr,
    const float* __restrict__ u_arr, const u64t* __restrict__ maxes,
    const float* __restrict__ s0_ws, const float* __restrict__ sl_ws,
    const float* __restrict__ sp_ws, const int* __restrict__ ck_ws,
    const int* __restrict__ ccnt, const u64t* __restrict__ cand,
    const u64t* __restrict__ mass, const u64t* __restrict__ band,
    const int* __restrict__ bandcnt, float* __restrict__ w_thr,
    int* __restrict__ w_bpM, double* __restrict__ w_seed, float* __restrict__ w_spD,
    float* __restrict__ out, int T, int V, int NL) {
  __shared__ u64t keyA[CAP];
  __shared__ int fh[NBINS];
  __shared__ float sredF[16];
  __shared__ int sredI[16];
  __shared__ u64t smax[NS];
  __shared__ float sp0[NS], spl[NS], spsp[NS];
  __shared__ int spck[NS];
  __shared__ float sh_thresh, sh_toklp, sh_spAdd;
  __shared__ double sh_seed;
  __shared__ int sh_cnt, sh_bp, sh_bCnt, sh_ckAdd;
  __shared__ u64t sh_bKeys[BANDCAP];
  __shared__ u64t sh_bMass[BANDCAP];
  __shared__ int  sh_bBin[BANDCAP];
  __shared__ u64t kb64[NSEL];
  __shared__ u64t kbs[NSEL];

  const int row = blockIdx.x;
  const int tid = threadIdx.x;
  const float* x  = logits + (size_t)row * V;
  const float* uu = u_arr  + (size_t)row * V;
  const float temp = temp_arr[row];
  const float minp = minp_arr[row];
  const float topp = topp_arr[row];
  const int   topk = topk_arr[row];
  const bool greedy = (temp < 1e-5f);
  const float st = greedy ? 1.0f : temp;
  const int V4 = V >> 2;
  const float4* x4 = (const float4*)x;

  if (tid < NS) {
    smax[tid] = maxes[row * NS + tid];
    sp0[tid] = s0_ws[row * NS + tid];
    spl[tid] = sl_ws[row * NS + tid];
    spsp[tid] = sp_ws[row * NS + tid];
    spck[tid] = ck_ws[row * NS + tid];
  }
  __syncthreads();
  u64t mk = smax[0];
  for (int w = 1; w < NS; ++w) { u64t t = smax[w]; if (t > mk) mk = t; }
  const float m0 = ordInv((unsigned int)(mk >> 32));
  const int gidx = (int)(~(unsigned int)mk);
  float S = spl[0], Sp = spsp[0];
  int ck = spck[0];
  for (int w = 1; w < NS; ++w) { S += spl[w]; Sp += spsp[w]; ck += spck[w]; }
  const float S0 = combineS0(smax, sp0, m0);
  const float ml = m0 / st;
  const float logS0 = logf(S0);
  const float rhs = minp * (1.0f / S);
  const float rhsS = rhs * S;
  const float rhsHi = rhsS * (1.0f + 1e-6f);
  const float rhsLo = rhsS * (1.0f - 1e-6f);
  auto keepTest = [&](float e) -> bool {
    if (e > rhsHi) return true;
    if (e < rhsLo) return false;
    return (e / S) >= rhs;
  };
  const bool deep = (!greedy && topk <= 0);
  const float scaleM = (float)MBINS / MWIN;

  // ----- resolve deferred min-p band elements (rare) -----
  const int bandTotal = greedy ? 0 : bandcnt[row];
  const bool bandOv = bandTotal > BANDCAP;
  if (tid == 0) { sh_bCnt = 0; sh_spAdd = 0.f; sh_ckAdd = 0; }
  __syncthreads();
  if (!greedy && !bandOv && bandTotal > 0 && minp > 0.f) {
    if (tid == 0) {
      for (int i = 0; i < bandTotal; ++i) sh_bKeys[i] = band[(size_t)row * BANDCAP + i];
      for (int i = 1; i < bandTotal; ++i) {
        u64t k = sh_bKeys[i]; int j = i - 1;
        while (j >= 0 && sh_bKeys[j] > k) { sh_bKeys[j + 1] = sh_bKeys[j]; j--; }
        sh_bKeys[j + 1] = k;
      }
      float spAdd = 0.f; int ckAdd = 0, bc = 0;
      for (int i = 0; i < bandTotal; ++i) {
        float vv = __uint_as_float((unsigned int)(sh_bKeys[i] & 0xffffffffu));
        float l = vv / st; float e = expf(l - ml);
        if ((e / S) >= rhs) {
          spAdd += e; ckAdd++;
          if (deep) {
            float fm = (m0 - vv) * scaleM;
            if (fm < (float)MBINS) { sh_bBin[bc] = (int)fm; sh_bMass[bc] = (u64t)((double)e * 4294967296.0); bc++; }
          }
        }
      }
      sh_spAdd = spAdd; sh_ckAdd = ckAdd; sh_bCnt = bc;
    }
    __syncthreads();
    Sp += sh_spAdd; ck += sh_ckAdd;
  } else if (!greedy && bandOv) {
    float sp2 = 0.f; int ck2 = 0;
    auto bodyR = [&](float vv) {
      float l = vv / st; float e = expf(l - ml);
      if (keepTest(e)) { sp2 += e; ck2++; }
    };
    for (int i4 = tid; i4 < V4; i4 += TPB) { float4 v = x4[i4]; bodyR(v.x); bodyR(v.y); bodyR(v.z); bodyR(v.w); }
    for (int i = (V4 << 2) + tid; i < V; i += TPB) bodyR(x[i]);
    Sp = blockSumF(sp2, sredF);
    ck = blockSumI(ck2, sredI);
  }

  // ----- candidates -----
  int cc = ccnt[row];
  int Cact = cc < CAP ? cc : CAP;
  int need = NSEL;
  if (topk > need) need = topk;
  if (need > CAP / 2) need = CAP / 2;
  if (need > V) need = V;
  bool fb = (cc > CAP) || (Cact < need);
  if (!fb) {
    for (int j = tid; j < Cact; j += TPB) keyA[j] = cand[(size_t)row * CAP + j];
  } else {
    const float bS = (float)NBINS / MWIN;
    for (int b = tid; b < NBINS; b += TPB) fh[b] = 0;
    if (tid == 0) sh_cnt = 0;
    __syncthreads();
    auto hb = [&](float vv) {
      float fbv = (m0 - vv) * bS;
      if (fbv < (float)NBINS) atomicAdd(&fh[(int)fbv], 1);
    };
    for (int i4 = tid; i4 < V4; i4 += TPB) { float4 v = x4[i4]; hb(v.x); hb(v.y); hb(v.z); hb(v.w); }
    for (int i = (V4 << 2) + tid; i < V; i += TPB) hb(x[i]);
    __syncthreads();
    if (tid == 0) {
      int cum = 0, B = -1;
      for (int b = 0; b < NBINS; ++b) { cum += fh[b]; if (cum >= need) { B = b; break; } }
      if (B < 0) B = NBINS - 1;
      sh_bp = B;
    }
    __syncthreads();
    const int B = sh_bp;
    auto cb = [&](float vv, int gi) {
      float fbv = (m0 - vv) * bS;
      if (fbv < (float)NBINS && (int)fbv <= B) {
        int pos = atomicAdd(&sh_cnt, 1);
        if (pos < CAP) keyA[pos] = ((u64t)fkeyDesc(vv) << 32) | (unsigned int)gi;
      }
    };
    for (int i4 = tid; i4 < V4; i4 += TPB) { float4 v = x4[i4]; int b = i4 << 2; cb(v.x, b); cb(v.y, b + 1); cb(v.z, b + 2); cb(v.w, b + 3); }
    for (int i = (V4 << 2) + tid; i < V; i += TPB) cb(x[i], i);
    __syncthreads();
    Cact = sh_cnt < CAP ? sh_cnt : CAP;
  }
  // ----- single sort by x (keyB derived from top-64 afterwards) -----
  __syncthreads();
  if (Cact <= 1024) {
    u64t ka = (tid < Cact) ? keyA[tid] : ~0ull;
    bitonicReg1024(ka, keyA);
  } else {
    int n = 128; while (n < Cact) n <<= 1;
    for (int i = Cact + tid; i < n; i += TPB) keyA[i] = ~0ull;
    __syncthreads();
    bitonicSortN(keyA, n);
  }
  // ----- top-NL by lp via rank-sort of top-64 (lp monotone in x; ties -> idx asc) -----
  {
    int M = Cact < NSEL ? Cact : NSEL;
    if (tid < M) {
      u64t ka = keyA[tid];
      float xv = fkeyInv((unsigned int)(ka >> 32));
      float lp = (xv - m0) - logS0;
      kb64[tid] = ((u64t)fkeyDesc(lp) << 32) | (ka & 0xffffffffu);
    }
    __syncthreads();
    if (tid < M) {
      u64t me = kb64[tid];
      int r = 0;
      for (int i = 0; i < M; ++i) r += (kb64[i] < me) ? 1 : 0;
      kbs[r] = me;
    }
    __syncthreads();
    float* o_idx  = out + T;
    float* o_lps  = out + T + (size_t)T * (NL + 1);
    for (int j = tid; j < NL; j += TPB) {
      if (j < M) {
        u64t kb = kbs[j];
        o_idx[(size_t)row * (NL + 1) + 1 + j] = (float)(unsigned int)(kb & 0xffffffffu);
        o_lps[(size_t)row * (NL + 1) + 1 + j] = fkeyInv((unsigned int)(kb >> 32));
      }
    }
  }

  // ----- sampling -----
  int sampled = -1;
  if (greedy) {
    sampled = gidx;
  } else if (topk > 0) {
    if (tid == 0) {
      int k = topk; if (k > V) k = V; if (k > CAP) k = CAP;
      int jp = 0; float cum = 0.f;
      for (int j = 0; j < k; ++j) {
        float pj = 0.f;
        if (j < ck && j < Cact) {
          float xv = fkeyInv((unsigned int)(keyA[j] >> 32));
          pj = expf(xv / st - ml) / Sp;
        }
        cum += pj;
        float ex = cum - pj;
        if (ex < topp) jp = j;
      }
      float thr;
      if (jp < ck && jp < Cact) {
        float xv = fkeyInv((unsigned int)(keyA[jp] >> 32));
        thr = xv / st;
      } else thr = -INFINITY;
      sh_thresh = thr;
    }
    __syncthreads();
    const float thr = sh_thresh;
    float bm = -INFINITY; int bi = 0x7fffffff;
    for (int j = tid; j < Cact; j += TPB) {
      u64t ka = keyA[j];
      float xv = fkeyInv((unsigned int)(ka >> 32));
      int gi = (int)(ka & 0xffffffffu);
      float l = xv / st;
      float e = expf(l - ml);
      if (keepTest(e) && l >= thr) {
        float uv = uu[gi];
        float g = -logf(-logf(uv));
        float val = l + g;
        if (val > bm || (val == bm && gi < bi)) { bm = val; bi = gi; }
      }
    }
    blockArgMaxF(bm, bi, sredF, sredI);
    sampled = bi;
  } else {
    // deep: mass combine (per-slice buffers + band) -> scan -> (bp, seed)
    if (!bandOv) {
      if (tid < MBINS) {
        u64t m = 0;
        for (int w = 0; w < NS; ++w) m += mass[((size_t)row * NS + w) * MBINS + tid];
        int bc = sh_bCnt;
        for (int j = 0; j < bc; ++j) if (sh_bBin[j] == tid) m += sh_bMass[j];
        keyA[tid] = m;
      }
    } else {
      for (int b = tid; b < MBINS; b += TPB) keyA[b] = 0ull;
      __syncthreads();
      auto bodyM = [&](float vv) {
        float l = vv / st; float e = expf(l - ml);
        if (keepTest(e)) {
          float fm = (m0 - vv) * scaleM;
          if (fm < (float)MBINS) atomicAdd(&keyA[(int)fm], (u64t)((double)e * 4294967296.0));
        }
      };
      for (int i4 = tid; i4 < V4; i4 += TPB) { float4 v = x4[i4]; bodyM(v.x); bodyM(v.y); bodyM(v.z); bodyM(v.w); }
      for (int i = (V4 << 2) + tid; i < V; i += TPB) bodyM(x[i]);
    }
    __syncthreads();
    u64t mh = (tid < MBINS) ? keyA[tid] : 0ull;
    for (int off = 1; off < MBINS; off <<= 1) {
      u64t add = (tid < MBINS && tid >= off) ? keyA[tid - off] : 0ull;
      __syncthreads();
      if (tid < MBINS) keyA[tid] += add;
      __syncthreads();
    }
    const double TP = (double)topp * (double)Sp;
    int q = -1; u64t myexcl = 0;
    if (tid < MBINS && mh > 0ull) {
      u64t excl = keyA[tid] - mh;
      if ((double)excl * (1.0 / 4294967296.0) < TP) { q = tid; myexcl = excl; }
    }
    int bp = blockMaxI(q, sredI);
    if (bp >= 0 && tid == bp) sh_seed = (double)myexcl * (1.0 / 4294967296.0);
    if (bp < 0 && tid == 0) sh_seed = 0.0;
    __syncthreads();
    if (tid == 0) {
      w_bpM[row] = bp;
      w_seed[row] = sh_seed;
      w_spD[row] = Sp;
      if (bp < 0) w_thr[row] = -INFINITY;
    }
  }

  // ----- token logprob + rank (non-deep only) -----
  if (!deep) {
    if (tid == 0) sh_toklp = (x[sampled] - m0) - logS0;
    __syncthreads();
    const float toklp = sh_toklp;
    int rc = 0;
    for (int j = tid; j < Cact; j += TPB) {
      float xv = fkeyInv((unsigned int)(keyA[j] >> 32));
      float lp = (xv - m0) - logS0;
      if (lp >= toklp) rc++;
    }
    int rank = blockSumI(rc, sredI);
    float* o_samp = out;
    float* o_idx  = out + T;
    float* o_lps  = out + T + (size_t)T * (NL + 1);
    float* o_rank = out + T + (size_t)2 * T * (NL + 1);
    if (tid == 0) {
      o_samp[row] = (float)sampled;
      o_idx[(size_t)row * (NL + 1)] = (float)sampled;
      o_lps[(size_t)row * (NL + 1)] = toklp;
      o_rank[row] = (float)rank;
    }
  }
}

// =================== KD: deep-row crossing-bin collect + sort + thr ===================
__global__ __launch_bounds__(TPB) void kD_thr(const float* __restrict__ logits,
    const float* __restrict__ temp_arr, const float* __restrict__ minp_arr,
    const float* __restrict__ topp_arr, const int* __restrict__ topk_arr,
    const u64t* __restrict__ maxes, const float* __restrict__ sl_ws,
    const int* __restrict__ w_bpM, const float* __restrict__ w_spD,
    const double* __restrict__ w_seed, float* __restrict__ w_thr, int V) {
  const int row = blockIdx.x, tid = threadIdx.x;
  const float temp = temp_arr[row];
  if (temp < 1e-5f || topk_arr[row] > 0) return;
  const int bp = w_bpM[row];
  if (bp < 0) return;
  __shared__ u64t keyA[CAP];
  __shared__ float pvals[CAP];
  __shared__ u64t smax[NS];
  __shared__ float ssl[NS];
  __shared__ int sh_cnt;
  if (tid < NS) { smax[tid] = maxes[row * NS + tid]; ssl[tid] = sl_ws[row * NS + tid]; }
  if (tid == 0) sh_cnt = 0;
  __syncthreads();
  u64t mk = smax[0];
  for (int w = 1; w < NS; ++w) { u64t t = smax[w]; if (t > mk) mk = t; }
  float S = ssl[0];
  for (int w = 1; w < NS; ++w) S += ssl[w];
  const float m0 = ordInv((unsigned int)(mk >> 32));
  const float st = temp;
  const float ml = m0 / st;
  const float minp = minp_arr[row];
  const float rhs = minp * (1.0f / S);
  const float rhsS = rhs * S;
  const float rhsHi = rhsS * (1.0f + 1e-6f);
  const float rhsLo = rhsS * (1.0f - 1e-6f);
  auto keepTest = [&](float e) -> bool {
    if (e > rhsHi) return true;
    if (e < rhsLo) return false;
    return (e / S) >= rhs;
  };
  const float scaleM = (float)MBINS / MWIN;
  const float* x = logits + (size_t)row * V;
  const int V4 = V >> 2;
  const float4* x4 = (const float4*)x;
  auto body = [&](float vv, int gi) {
    float fm = (m0 - vv) * scaleM;
    if (fm < (float)MBINS && (int)fm == bp) {
      float l = vv / st;
      float e = expf(l - ml);
      if (keepTest(e)) {
        int pos = atomicAdd(&sh_cnt, 1);
        if (pos < CAP) keyA[pos] = ((u64t)fkeyDesc(vv) << 32) | (unsigned int)gi;
      }
    }
  };
  for (int i4 = tid; i4 < V4; i4 += TPB) {
    float4 v = x4[i4]; int b = i4 << 2;
    body(v.x, b); body(v.y, b + 1); body(v.z, b + 2); body(v.w, b + 3);
  }
  for (int i = (V4 << 2) + tid; i < V; i += TPB) body(x[i], i);
  __syncthreads();
  int C5 = sh_cnt < CAP ? sh_cnt : CAP;
  if (C5 <= 1024) {
    u64t kc = (tid < C5) ? keyA[tid] : ~0ull;
    bitonicReg1024(kc, keyA);
  } else {
    int n5 = 128; while (n5 < C5) n5 <<= 1;
    for (int i = C5 + tid; i < n5; i += TPB) keyA[i] = ~0ull;
    __syncthreads();
    bitonicSortN(keyA, n5);
  }
  const float Sp = w_spD[row];
  for (int j = tid; j < C5; j += TPB) {
    float xv = fkeyInv((unsigned int)(keyA[j] >> 32));
    pvals[j] = expf(xv / st - ml) / Sp;
  }
  __syncthreads();
  if (tid == 0) {
    const float topp = topp_arr[row];
    float cum = (float)(w_seed[row] / (double)Sp);
    float lastVal = fkeyInv((unsigned int)(keyA[0] >> 32));
    for (int j = 0; j < C5; ++j) {
      float pj = pvals[j];
      cum += pj;
      float ex = cum - pj;
      if (ex < topp) lastVal = fkeyInv((unsigned int)(keyA[j] >> 32));
    }
    w_thr[row] = lastVal / st;
  }
}

// =================== K6: sliced Gumbel argmax for deep rows ===================
__global__ __launch_bounds__(TPBS) void k6_gumbel(const float* __restrict__ logits,
    const float* __restrict__ temp_arr, const float* __restrict__ minp_arr,
    const int* __restrict__ topk_arr, const float* __restrict__ u_arr,
    const u64t* __restrict__ maxes, const float* __restrict__ sl_ws,
    const float* __restrict__ w_thr, u64t* __restrict__ gkey, int V) {
  const int row = blockIdx.y, s = blockIdx.x, tid = threadIdx.x;
  const float temp = temp_arr[row];
  if (temp < 1e-5f || topk_arr[row] > 0) return;
  __shared__ u64t smax[NS];
  __shared__ float ssl[NS];
  __shared__ float sredF[16];
  __shared__ int sredI[16];
  if (tid < NS) { smax[tid] = maxes[row * NS + tid]; ssl[tid] = sl_ws[row * NS + tid]; }
  __syncthreads();
  u64t mk = smax[0];
  for (int w = 1; w < NS; ++w) { u64t t = smax[w]; if (t > mk) mk = t; }
  float S = ssl[0];
  for (int w = 1; w < NS; ++w) S += ssl[w];
  const float m0 = ordInv((unsigned int)(mk >> 32));
  const float st = temp;
  const float ml = m0 / st;
  const float minp = minp_arr[row];
  const float rhs = minp * (1.0f / S);
  const float rhsS = rhs * S;
  const float rhsHi = rhsS * (1.0f + 1e-6f);
  const float rhsLo = rhsS * (1.0f - 1e-6f);
  auto keepTest = [&](float e) -> bool {
    if (e > rhsHi) return true;
    if (e < rhsLo) return false;
    return (e / S) >= rhs;
  };
  const float thr = w_thr[row];
  const float* x  = logits + (size_t)row * V;
  const float* uu = u_arr  + (size_t)row * V;
  const int V4 = V >> 2;
  const float4* x4 = (const float4*)x;
  const float4* u4 = (const float4*)uu;
  const int a4 = (int)(((long long)V4 * s) / NS), b4 = (int)(((long long)V4 * (s + 1)) / NS);
  float bm = -INFINITY; int bi = 0x7fffffff;
  auto body = [&](float vv, float uv, int gi) {
    float l = vv / st;
    float e = expf(l - ml);
    if (keepTest(e) && l >= thr) {
      float g = -logf(-logf(uv));
      float val = l + g;
      if (val > bm || (val == bm && gi < bi)) { bm = val; bi = gi; }
    }
  };
  for (int i4 = a4 + tid; i4 < b4; i4 += TPBS) {
    float4 v = x4[i4]; float4 w = u4[i4]; int b = i4 << 2;
    body(v.x, w.x, b); body(v.y, w.y, b + 1); body(v.z, w.z, b + 2); body(v.w, w.w, b + 3);
  }
  if (s == NS - 1) for (int i = (V4 << 2) + tid; i < V; i += TPBS) body(x[i], uu[i], i);
  blockArgMaxF(bm, bi, sredF, sredI);
  if (tid == 0) gkey[row * NS + s] = mkMaxKey(bm, bi);
}

// =================== K7: deep-row finalize ===================
__global__ __launch_bounds__(TPB) void k7_deepfin(const float* __restrict__ logits,
    const float* __restrict__ temp_arr, const int* __restrict__ topk_arr,
    const u64t* __restrict__ gkey, const float* __restrict__ s0_ws,
    const u64t* __restrict__ maxes, float* __restrict__ out, int T, int V, int NL) {
  const int row = blockIdx.x, tid = threadIdx.x;
  const float temp = temp_arr[row];
  if (temp < 1e-5f || topk_arr[row] > 0) return;
  __shared__ u64t sg[NS];
  __shared__ u64t smax[NS];
  __shared__ float sp0[NS];
  __shared__ int sredI[16];
  if (tid < NS) { sg[tid] = gkey[row * NS + tid]; smax[tid] = maxes[row * NS + tid]; sp0[tid] = s0_ws[row * NS + tid]; }
  __syncthreads();
  u64t gk = sg[0];
  for (int w = 1; w < NS; ++w) { if (sg[w] > gk) gk = sg[w]; }
  u64t mk = smax[0];
  for (int w = 1; w < NS; ++w) { u64t t = smax[w]; if (t > mk) mk = t; }
  const float m0 = ordInv((unsigned int)(mk >> 32));
  const float S0 = combineS0(smax, sp0, m0);
  const float logS0 = logf(S0);
  const int sampled = (int)(~(unsigned int)gk);
  const float* x = logits + (size_t)row * V;
  const float toklp = (x[sampled] - m0) - logS0;
  const int V4 = V >> 2;
  const float4* x4 = (const float4*)x;
  int rc = 0;
  auto body = [&](float vv) {
    float lp = (vv - m0) - logS0;
    if (lp >= toklp) rc++;
  };
  for (int i4 = tid; i4 < V4; i4 += TPB) { float4 v = x4[i4]; body(v.x); body(v.y); body(v.z); body(v.w); }
  for (int i = (V4 << 2) + tid; i < V; i += TPB) body(x[i]);
  int rank = blockSumI(rc, sredI);
  float* o_samp = out;
  float* o_idx  = out + T;
  float* o_lps  = out + T + (size_t)T * (NL + 1);
  float* o_rank = out + T + (size_t)2 * T * (NL + 1);
  if (tid == 0) {
    o_samp[row] = (float)sampled;
    o_idx[(size_t)row * (NL + 1)] = (float)sampled;
    o_lps[(size_t)row * (NL + 1)] = toklp;
    o_rank[row] = (float)rank;
  }
}

// =================== monolithic fallback (used if ws too small) ===================
__global__ __launch_bounds__(TPB) void sampler_mono(
    const float* __restrict__ logits, const float* __restrict__ temp_arr,
    const float* __restrict__ minp_arr, const float* __restrict__ topp_arr,
    const int* __restrict__ topk_arr, const float* __restrict__ u_arr,
    float* __restrict__ out, int T, int V, int NL) {
  __shared__ u64t keyA[CAP];
  __shared__ u64t keyB[CAP];
  __shared__ float pvals[CAP];
  __shared__ int   cnthist[NBINS];
  __shared__ u64t  masshist[NBINS];
  __shared__ float sredF[16];
  __shared__ int   sredI[16];
  __shared__ float sh_thresh, sh_toklp, sh_Rm, sh_Roff;
  __shared__ double sh_seedD, sh_seedBase;
  __shared__ int sh_B64, sh_Bp, sh_cnt, sh_state;

  const int row = blockIdx.x;
  const int tid = threadIdx.x;
  const float* x  = logits + (size_t)row * V;
  const float* uu = u_arr  + (size_t)row * V;
  const float temp = temp_arr[row];
  const float minp = minp_arr[row];
  const float topp = topp_arr[row];
  const int   topk = topk_arr[row];
  const bool greedy = (temp < 1e-5f);
  const float st = greedy ? 1.0f : temp;
  const int V4 = V >> 2;
  const float4* x4 = (const float4*)x;

  float m0; int gidx;
  {
    float lm = -INFINITY; int lidx = 0x7fffffff;
    for (int i4 = tid; i4 < V4; i4 += TPB) {
      float4 v = x4[i4]; int b = i4 << 2;
      if (v.x > lm) { lm = v.x; lidx = b; }
      if (v.y > lm) { lm = v.y; lidx = b + 1; }
      if (v.z > lm) { lm = v.z; lidx = b + 2; }
      if (v.w > lm) { lm = v.w; lidx = b + 3; }
    }
    for (int i = (V4 << 2) + tid; i < V; i += TPB) {
      float v = x[i]; if (v > lm) { lm = v; lidx = i; }
    }
    blockArgMaxF(lm, lidx, sredF, sredI);
    m0 = lm; gidx = lidx;
  }
  const float ml = m0 / st;

  float Rcur = 2.0f;
  float binScale = (float)NBINS / Rcur;
  for (int b = tid; b < NBINS; b += TPB) cnthist[b] = 0;
  __syncthreads();
  float S0, S;
  {
    float s0p = 0.f, slp = 0.f;
    auto histAdd = [&](float vv) {
      float fb = (m0 - vv) * binScale;
      if (fb < (float)NBINS) atomicAdd(&cnthist[(int)fb], 1);
    };
    for (int i4 = tid; i4 < V4; i4 += TPB) {
      float4 v = x4[i4];
      s0p += expf(v.x - m0) + expf(v.y - m0) + expf(v.z - m0) + expf(v.w - m0);
      if (!greedy) slp += expf(v.x / st - ml) + expf(v.y / st - ml) + expf(v.z / st - ml) + expf(v.w / st - ml);
      histAdd(v.x); histAdd(v.y); histAdd(v.z); histAdd(v.w);
    }
    for (int i = (V4 << 2) + tid; i < V; i += TPB) {
      float v = x[i]; s0p += expf(v - m0); if (!greedy) slp += expf(v / st - ml); histAdd(v);
    }
    S0 = blockSumF(s0p, sredF);
    S = greedy ? S0 : blockSumF(slp, sredF);
  }

  int need = NSEL;
  if (topk > need) need = topk;
  if (need > CAP / 2) need = CAP / 2;
  if (need > V) need = V;
  int B64;
  for (int attempt = 0; ; ++attempt) {
    __syncthreads();
    if (tid == 0) {
      long long cum = 0; int b64 = -1; long long c64 = 0;
      for (int b = 0; b < NBINS; ++b) {
        cum += cnthist[b];
        if (cum >= need) { b64 = b; c64 = cum; break; }
      }
      int state;
      if (b64 >= 0 && c64 <= CAP) state = 1;
      else if (b64 < 0) state = 0;
      else state = 2;
      if (attempt >= 3 && state != 1) { state = 1; if (b64 < 0) b64 = NBINS - 1; }
      sh_state = state; sh_B64 = b64;
    }
    __syncthreads();
    if (sh_state == 1) { B64 = sh_B64; break; }
    Rcur = (sh_state == 0) ? Rcur * 8.0f : Rcur * 0.125f;
    binScale = (float)NBINS / Rcur;
    __syncthreads();
    for (int b = tid; b < NBINS; b += TPB) cnthist[b] = 0;
    __syncthreads();
    auto histAdd2 = [&](float vv) {
      float fb = (m0 - vv) * binScale;
      if (fb < (float)NBINS) atomicAdd(&cnthist[(int)fb], 1);
    };
    for (int i4 = tid; i4 < V4; i4 += TPB) {
      float4 v = x4[i4];
      histAdd2(v.x); histAdd2(v.y); histAdd2(v.z); histAdd2(v.w);
    }
    for (int i = (V4 << 2) + tid; i < V; i += TPB) histAdd2(x[i]);
  }

  const float logS0 = logf(S0);
  const float rhs = minp * (1.0f / S);
  const float rhsS = rhs * S;
  const float rhsHi = rhsS * (1.0f + 1e-6f);
  const float rhsLo = rhsS * (1.0f - 1e-6f);
  auto keepTest = [&](float e) -> bool {
    if (e > rhsHi) return true;
    if (e < rhsLo) return false;
    return (e / S) >= rhs;
  };
  const bool needMass = (!greedy && topk <= 0);
  const float scaleM0 = (float)NBINS / 16.0f;

  for (int b = tid; b < NBINS; b += TPB) { cnthist[b] = 0; masshist[b] = 0ull; }
  if (tid == 0) { sh_cnt = 0; sh_Rm = 16.0f; sh_Roff = 0.0f; sh_seedBase = 0.0; }
  __syncthreads();
  float Sp; int ck;
  {
    float spp = 0.f; int ckp = 0;
    auto bodyB = [&](float vv, int gi) {
      float fb = (m0 - vv) * binScale;
      if (fb < (float)NBINS && (int)fb <= B64) {
        int pos = atomicAdd(&sh_cnt, 1);
        if (pos < CAP) keyA[pos] = ((u64t)fkeyDesc(vv) << 32) | (unsigned int)gi;
      }
      if (!greedy) {
        float l = vv / st;
        float e = expf(l - ml);
        if (keepTest(e)) {
          spp += e; ckp++;
          if (needMass) {
            float fm = (m0 - vv) * scaleM0;
            if (fm < (float)NBINS) {
              int bm = (int)fm;
              atomicAdd(&masshist[bm], (u64t)((double)e * 4294967296.0));
              atomicAdd(&cnthist[bm], 1);
            }
          }
        }
      }
    };
    for (int i4 = tid; i4 < V4; i4 += TPB) {
      float4 v = x4[i4]; int b = i4 << 2;
      bodyB(v.x, b); bodyB(v.y, b + 1); bodyB(v.z, b + 2); bodyB(v.w, b + 3);
    }
    for (int i = (V4 << 2) + tid; i < V; i += TPB) bodyB(x[i], i);
    Sp = blockSumF(spp, sredF);
    ck = blockSumI(ckp, sredI);
  }
  int Cact = sh_cnt; if (Cact > CAP) Cact = CAP;

  int n = 128; while (n < Cact) n <<= 1;
  for (int i = Cact + tid; i < n; i += TPB) keyA[i] = ~0ull;
  __syncthreads();
  bitonicSortN(keyA, n);
  for (int j = tid; j < n; j += TPB) {
    if (j < Cact) {
      u64t ka = keyA[j];
      float xv = fkeyInv((unsigned int)(ka >> 32));
      float lp = (xv - m0) - logS0;
      keyB[j] = ((u64t)fkeyDesc(lp) << 32) | (ka & 0xffffffffu);
    } else keyB[j] = ~0ull;
  }
  bitonicSortN(keyB, n);

  int sampled;
  if (greedy) {
    sampled = gidx;
  } else if (topk > 0) {
    if (tid == 0) {
      int k = topk; if (k > V) k = V; if (k > CAP) k = CAP;
      int jp = 0; float cum = 0.f;
      for (int j = 0; j < k; ++j) {
        float pj = 0.f;
        if (j < ck && j < Cact) {
          float xv = fkeyInv((unsigned int)(keyA[j] >> 32));
          pj = expf(xv / st - ml) / Sp;
        }
        cum += pj;
        float ex = cum - pj;
        if (ex < topp) jp = j;
      }
      float thr;
      if (jp < ck && jp < Cact) {
        float xv = fkeyInv((unsigned int)(keyA[jp] >> 32));
        thr = xv / st;
      } else thr = -INFINITY;
      sh_thresh = thr;
    }
    __syncthreads();
    const float thr = sh_thresh;
    float bm = -INFINITY; int bi = 0x7fffffff;
    for (int j = tid; j < Cact; j += TPB) {
      u64t ka = keyA[j];
      float xv = fkeyInv((unsigned int)(ka >> 32));
      int gi = (int)(ka & 0xffffffffu);
      float l = xv / st;
      float e = expf(l - ml);
      if (keepTest(e) && l >= thr) {
        float uv = uu[gi];
        float g = -logf(-logf(uv));
        float val = l + g;
        if (val > bm || (val == bm && gi < bi)) { bm = val; bi = gi; }
      }
    }
    blockArgMaxF(bm, bi, sredF, sredI);
    sampled = bi;
  } else {
    for (int attempt = 0; ; ++attempt) {
      __syncthreads();
      if (tid == 0) {
        float Rm = sh_Rm, Roff = sh_Roff;
        double TP = (double)topp * (double)Sp;
        double cm = sh_seedBase; int bp = -1; double seed = sh_seedBase; int cbp = 0;
        for (int b = 0; b < NBINS; ++b) {
          u64t mh = masshist[b];
          if (mh > 0ull && cm < TP) { bp = b; seed = cm; cbp = cnthist[b]; }
          cm += (double)mh * (1.0 / 4294967296.0);
        }
        int state = 1;
        if (attempt < 3) {
          if (cm < TP && Roff == 0.0f) {
            state = 0; sh_Rm = Rm * 8.0f;
          } else if (bp >= 0 && cbp > CAP) {
            state = 2;
            float bw = Rm / (float)NBINS;
            sh_Roff = Roff + (float)bp * bw;
            sh_Rm = bw;
            sh_seedBase = seed;
          }
        }
        if (bp < 0) { bp = 0; seed = sh_seedBase; }
        sh_Bp = bp; sh_seedD = seed; sh_state = state;
      }
      __syncthreads();
      if (sh_state == 1) break;
      float Rm = sh_Rm, Roff = sh_Roff;
      float sM = (float)NBINS / Rm;
      for (int b = tid; b < NBINS; b += TPB) { cnthist[b] = 0; masshist[b] = 0ull; }
      __syncthreads();
      auto bodyM = [&](float vv) {
        float fm = ((m0 - vv) - Roff) * sM;
        if (fm >= 0.f && fm < (float)NBINS) {
          float l = vv / st;
          float e = expf(l - ml);
          if (keepTest(e)) {
            int bm = (int)fm;
            atomicAdd(&masshist[bm], (u64t)((double)e * 4294967296.0));
            atomicAdd(&cnthist[bm], 1);
          }
        }
      };
      for (int i4 = tid; i4 < V4; i4 += TPB) {
        float4 v = x4[i4]; bodyM(v.x); bodyM(v.y); bodyM(v.z); bodyM(v.w);
      }
      for (int i = (V4 << 2) + tid; i < V; i += TPB) bodyM(x[i]);
    }
    const int Bp = sh_Bp;
    const float RmF = sh_Rm, RoffF = sh_Roff;
    const float sM = (float)NBINS / RmF;
    if (tid == 0) sh_cnt = 0;
    __syncthreads();
    auto bodyC = [&](float vv, int gi) {
      float fm = ((m0 - vv) - RoffF) * sM;
      if (fm >= 0.f && fm < (float)NBINS && (int)fm == Bp) {
        float l = vv / st;
        float e = expf(l - ml);
        if (keepTest(e)) {
          int pos = atomicAdd(&sh_cnt, 1);
          if (pos < CAP) keyA[pos] = ((u64t)fkeyDesc(vv) << 32) | (unsigned int)gi;
        }
      }
    };
    for (int i4 = tid; i4 < V4; i4 += TPB) {
      float4 v = x4[i4]; int b = i4 << 2;
      bodyC(v.x, b); bodyC(v.y, b + 1); bodyC(v.z, b + 2); bodyC(v.w, b + 3);
    }
    for (int i = (V4 << 2) + tid; i < V; i += TPB) bodyC(x[i], i);
    __syncthreads();
    int C5 = sh_cnt; if (C5 > CAP) C5 = CAP;
    int n5 = 128; while (n5 < C5) n5 <<= 1;
    for (int i = C5 + tid; i < n5; i += TPB) keyA[i] = ~0ull;
    __syncthreads();
    bitonicSortN(keyA, n5);
    for (int j = tid; j < C5; j += TPB) {
      float xv = fkeyInv((unsigned int)(keyA[j] >> 32));
      pvals[j] = expf(xv / st - ml) / Sp;
    }
    __syncthreads();
    if (tid == 0) {
      float cum = (float)(sh_seedD / (double)Sp);
      float lastVal = fkeyInv((unsigned int)(keyA[0] >> 32));
      for (int j = 0; j < C5; ++j) {
        float pj = pvals[j];
        cum += pj;
        float ex = cum - pj;
        if (ex < topp) lastVal = fkeyInv((unsigned int)(keyA[j] >> 32));
      }
      sh_thresh = lastVal / st;
    }
    __syncthreads();
    const float thr = sh_thresh;
    const float4* u4 = (const float4*)uu;
    float bm = -INFINITY; int bi = 0x7fffffff;
    auto body6 = [&](float vv, float uv, int gi) {
      float l = vv / st;
      float e = expf(l - ml);
      if (keepTest(e) && l >= thr) {
        float g = -logf(-logf(uv));
        float val = l + g;
        if (val > bm || (val == bm && gi < bi)) { bm = val; bi = gi; }
      }
    };
    for (int i4 = tid; i4 < V4; i4 += TPB) {
      float4 v = x4[i4]; float4 w = u4[i4]; int b = i4 << 2;
      body6(v.x, w.x, b); body6(v.y, w.y, b + 1); body6(v.z, w.z, b + 2); body6(v.w, w.w, b + 3);
    }
    for (int i = (V4 << 2) + tid; i < V; i += TPB) body6(x[i], uu[i], i);
    blockArgMaxF(bm, bi, sredF, sredI);
    sampled = bi;
  }

  if (tid == 0) sh_toklp = (x[sampled] - m0) - logS0;
  __syncthreads();
  const float toklp = sh_toklp;
  int rank;
  {
    int rc = 0;
    if (!needMass) {
      for (int j = tid; j < Cact; j += TPB) {
        float xv = fkeyInv((unsigned int)(keyA[j] >> 32));
        float lp = (xv - m0) - logS0;
        if (lp >= toklp) rc++;
      }
    } else {
      auto body7 = [&](float vv) {
        float lp = (vv - m0) - logS0;
        if (lp >= toklp) rc++;
      };
      for (int i4 = tid; i4 < V4; i4 += TPB) {
        float4 v = x4[i4]; body7(v.x); body7(v.y); body7(v.z); body7(v.w);
      }
      for (int i = (V4 << 2) + tid; i < V; i += TPB) body7(x[i]);
    }
    rank = blockSumI(rc, sredI);
  }

  float* o_samp = out;
  float* o_idx  = out + T;
  float* o_lps  = out + T + (size_t)T * (NL + 1);
  float* o_rank = out + T + (size_t)2 * T * (NL + 1);
  if (tid == 0) {
    o_samp[row] = (float)sampled;
    o_idx[(size_t)row * (NL + 1)] = (float)sampled;
    o_lps[(size_t)row * (NL + 1)] = toklp;
    o_rank[row] = (float)rank;
  }
  for (int j = tid; j < NL; j += TPB) {
    u64t kb = keyB[j];
    o_idx[(size_t)row * (NL + 1) + 1 + j] = (float)(unsigned int)(kb & 0xffffffffu);
    o_lps[(size_t)row * (NL + 1) + 1 + j] = fkeyInv((unsigned int)(kb >> 32));
  }
}

extern "C" void kernel_launch(void* const* d_in, const int* in_sizes, int n_in,
                              void* d_out, int out_size, void* d_ws, size_t ws_size,
                              hipStream_t stream) {
  const float* logits = (const float*)d_in[0];
  const float* temp   = (const float*)d_in[1];
  const float* minp   = (const float*)d_in[2];
  const float* topp   = (const float*)d_in[3];
  const int*   topk   = (const int*)d_in[4];
  const float* u      = (const float*)d_in[5];
  const int T  = in_sizes[1];
  const int V  = in_sizes[0] / T;
  const int NL = (out_size / T - 4) / 2;

  // ws layout (8-byte entries first)
  size_t off = 0;
  char* base = (char*)d_ws;
  u64t*   w_maxes   = (u64t*)(base + off);   off += (size_t)T * NS * 8;
  u64t*   w_cand    = (u64t*)(base + off);   off += (size_t)T * CAP * 8;
  u64t*   w_mass    = (u64t*)(base + off);   off += (size_t)T * NS * MBINS * 8;  // per-slice
  u64t*   w_gkey    = (u64t*)(base + off);   off += (size_t)T * NS * 8;
  u64t*   w_band    = (u64t*)(base + off);   off += (size_t)T * BANDCAP * 8;
  double* w_seed    = (double*)(base + off); off += (size_t)T * 8;
  float*  w_s0      = (float*)(base + off);  off += (size_t)T * NS * 4;
  float*  w_sl      = (float*)(base + off);  off += (size_t)T * NS * 4;
  float*  w_sp      = (float*)(base + off);  off += (size_t)T * NS * 4;
  int*    w_ck      = (int*)(base + off);    off += (size_t)T * NS * 4;
  int*    w_ccnt    = (int*)(base + off);    off += (size_t)T * 4;
  int*    w_bandcnt = (int*)(base + off);    off += (size_t)T * 4;
  float*  w_thr     = (float*)(base + off);  off += (size_t)T * 4;
  int*    w_bpM     = (int*)(base + off);    off += (size_t)T * 4;
  float*  w_spD     = (float*)(base + off);  off += (size_t)T * 4;

  if (off > ws_size) {
    sampler_mono<<<T, TPB, 0, stream>>>(logits, temp, minp, topp, topk, u,
                                        (float*)d_out, T, V, NL);
    return;
  }

  dim3 gS(NS, T);
  k1_max<<<gS, TPBS, 0, stream>>>(logits, w_maxes, w_s0, w_ccnt, w_bandcnt, V);
  k2_all<<<gS, TPBS, 0, stream>>>(logits, temp, minp, topk, w_maxes, w_sl,
                                  w_sp, w_ck, w_ccnt, w_cand, w_bandcnt, w_band,
                                  w_mass, V);
  k5_final<<<T, TPB, 0, stream>>>(logits, temp, minp, topp, topk, u, w_maxes,
                                  w_s0, w_sl, w_sp, w_ck, w_ccnt, w_cand, w_mass,
                                  w_band, w_bandcnt, w_thr, w_bpM, w_seed, w_spD,
                                  (float*)d_out, T, V, NL);
  kD_thr<<<T, TPB, 0, stream>>>(logits, temp, minp, topp, topk, w_maxes, w_sl,
                                w_bpM, w_spD, w_seed, w_thr, V);
  k6_gumbel<<<gS, TPBS, 0, stream>>>(logits, temp, minp, topk, u, w_maxes, w_sl,
                                     w_thr, w_gkey, V);
  k7_deepfin<<<T, TPB, 0, stream>>>(logits, temp, topk, w_gkey, w_s0, w_maxes,
                                    (float*)d_out, T, V, NL);
}